// Round 7
// baseline (429.131 us; speedup 1.0000x reference)
//
#include <hip/hip_runtime.h>
#include <cstdint>
#include <cstddef>

#define TPB 256
#define BCAP 2560      // bucket capacity: mean 2046, sigma ~45 -> 11 sigma headroom
#define NBKMAX 800     // max buckets in LDS (n=100k -> 782)
#define EPB 8192       // edges per multisplit block

typedef short bf16x8 __attribute__((ext_vector_type(8)));
typedef float f32x4 __attribute__((ext_vector_type(4)));

__device__ __forceinline__ unsigned short f2bf(float f) {
  unsigned int u = __float_as_uint(f);
  unsigned int r = (u + 0x7fffu + ((u >> 16) & 1u)) >> 16;  // RNE
  return (unsigned short)r;
}
__device__ __forceinline__ float bf2f(unsigned short h) {
  return __uint_as_float(((unsigned int)h) << 16);
}

// async 16B global->LDS DMA. LDS dest is wave-uniform base + lane*16.
__device__ __forceinline__ void gload16(const void* g, void* l) {
  __builtin_amdgcn_global_load_lds(
      (const __attribute__((address_space(1))) unsigned int*)g,
      (__attribute__((address_space(3))) unsigned int*)l, 16, 0, 0);
}

// counted vmcnt wait: wait until <= N vector-memory ops outstanding.
template <int N>
__device__ __forceinline__ void waitvm() {
  asm volatile("s_waitcnt vmcnt(%0)" ::"n"(N) : "memory");
}

// ---------------- bucketed CSR build (multisplit, R4-proven) ----------------

__global__ __launch_bounds__(256) void multisplit_scatter(
    const int* __restrict__ src, const int* __restrict__ dst,
    unsigned int* __restrict__ be, int* __restrict__ bcnt, int e, int nbk) {
  __shared__ int hist[NBKMAX];
  __shared__ int curs[NBKMAX];
  int tx = threadIdx.x;
  int e0 = blockIdx.x * EPB;
  int e1 = min(e, e0 + EPB);

  for (int b = tx; b < nbk; b += TPB) hist[b] = 0;
  __syncthreads();
  for (int i = e0 + tx; i < e1; i += TPB) atomicAdd(&hist[dst[i] >> 7], 1);
  __syncthreads();
  int rot = (blockIdx.x * 131) % nbk;
  for (int s = tx; s < nbk; s += TPB) {
    int b = s + rot;
    if (b >= nbk) b -= nbk;
    int h = hist[b];
    curs[b] = (h > 0) ? atomicAdd(&bcnt[b], h) : 0;
  }
  __syncthreads();
  for (int i = e0 + tx; i < e1; i += TPB) {
    int d = dst[i];
    int b = d >> 7;
    int p = atomicAdd(&curs[b], 1);
    if (p < BCAP)
      be[(size_t)b * BCAP + p] = ((unsigned int)(d & 127) << 17) | (unsigned int)src[i];
  }
}

__global__ void bucket_scan(const int* __restrict__ bcnt, int* __restrict__ bbase, int nbk) {
  __shared__ int s[TPB];
  __shared__ int carry;
  int tx = threadIdx.x;
  if (tx == 0) carry = 0;
  __syncthreads();
  for (int base = 0; base < nbk; base += TPB) {
    int i = base + tx;
    int v = (i < nbk) ? bcnt[i] : 0;
    s[tx] = v;
    __syncthreads();
    for (int d = 1; d < TPB; d <<= 1) {
      int t = (tx >= d) ? s[tx - d] : 0;
      __syncthreads();
      s[tx] += t;
      __syncthreads();
    }
    int c = carry;
    if (i < nbk) bbase[i] = c + s[tx] - v;
    __syncthreads();
    if (tx == TPB - 1) carry = c + s[tx];
    __syncthreads();
  }
}

__global__ __launch_bounds__(256) void per_bucket_build(
    const unsigned int* __restrict__ be, const int* __restrict__ bcnt,
    const int* __restrict__ bbase, int* __restrict__ off, int* __restrict__ col,
    int n, int e) {
  int b = blockIdx.x, tx = threadIdx.x;
  int cnt = bcnt[b];
  if (cnt > BCAP) cnt = BCAP;
  int base = bbase[b];
  int node0 = b << 7;
  __shared__ int scnt[128];
  __shared__ int sscan[128];
  if (tx < 128) scnt[tx] = 0;
  __syncthreads();
  const unsigned int* eb = be + (size_t)b * BCAP;
  for (int i = tx; i < cnt; i += 256) atomicAdd(&scnt[eb[i] >> 17], 1);
  __syncthreads();
  if (tx < 128) sscan[tx] = scnt[tx];
  __syncthreads();
  for (int d = 1; d < 128; d <<= 1) {
    int t = 0;
    if (tx < 128 && tx >= d) t = sscan[tx - d];
    __syncthreads();
    if (tx < 128) sscan[tx] += t;
    __syncthreads();
  }
  if (tx < 128) {
    int excl = sscan[tx] - scnt[tx];
    if (node0 + tx < n) off[node0 + tx] = base + excl;
    scnt[tx] = excl;  // becomes fill cursor
  }
  if (b == 0 && tx == 0) off[n] = e;
  __syncthreads();
  for (int i = tx; i < cnt; i += 256) {
    unsigned int u = eb[i];
    int p = atomicAdd(&scnt[u >> 17], 1);
    col[base + p] = (int)(u & 0x1ffff);
  }
}

// ---------------- converts ----------------

__global__ void f32_to_bf16_v4(const float* __restrict__ in, unsigned short* __restrict__ out,
                               int n4) {
  int i = blockIdx.x * TPB + threadIdx.x;
  if (i >= n4) return;
  float4 v = ((const float4*)in)[i];
  ushort4 o;
  o.x = f2bf(v.x); o.y = f2bf(v.y); o.z = f2bf(v.z); o.w = f2bf(v.w);
  ((ushort4*)out)[i] = o;
}

__global__ void make_dropmask(const float* __restrict__ u, unsigned char* __restrict__ m,
                              int n4) {
  int i = blockIdx.x * TPB + threadIdx.x;
  if (i >= n4) return;
  float4 v = ((const float4*)u)[i];
  uchar4 o;
  o.x = (v.x >= 0.2f) ? 1 : 0;
  o.y = (v.y >= 0.2f) ? 1 : 0;
  o.z = (v.z >= 0.2f) ? 1 : 0;
  o.w = (v.w >= 0.2f) ? 1 : 0;
  ((uchar4*)m)[i] = o;
}

// layer-1 weights: Wt1[128 out][256 K] = concat(W1l;W1r) transposed
template <int NF>
__global__ void build_wt(const float* __restrict__ Wl, const float* __restrict__ Wr,
                         unsigned short* __restrict__ Wt) {
  int idx = blockIdx.x * TPB + threadIdx.x;
  if (idx >= NF * 256) return;
  int nn = idx >> 8;
  int k = idx & 255;
  float v = (k < 128) ? Wl[k * NF + nn] : Wr[(k - 128) * NF + nn];
  Wt[idx] = f2bf(v);
}

// layer-2' weights: Wt2[128 out][128 K]; rows 0-63 = W2l^T (-> P), 64-127 = W2r^T (-> Q)
__global__ void build_wt2p(const float* __restrict__ W2l, const float* __restrict__ W2r,
                           unsigned short* __restrict__ Wt) {
  int idx = blockIdx.x * TPB + threadIdx.x;
  if (idx >= 128 * 128) return;
  int nn = idx >> 7;
  int k = idx & 127;
  float v = (nn < 64) ? W2l[k * 64 + nn] : W2r[k * 64 + (nn - 64)];
  Wt[idx] = f2bf(v);
}

// ---------------- layer-1 mean aggregation: 16 lanes per node (R3-proven) ----------
// One wave = 4 nodes. Per chunk of 16 edges, lane li preloads col[s0+base+li]
// (clamped to s1-1), then 16 unrolled iterations broadcast c via shfl(width=16)
// and gather uint4 at X + c*128 + li*8. Stable at 66us / 177MB FETCH / 3.1TB/s
// across 4 rewrites -> treated as the random-gather floor. R5's 2-node
// interleave SPILLED (VGPR pressure); do not widen without resource check.

__global__ void aggregate_bf(const unsigned short* __restrict__ X,
                             const int* __restrict__ off, const int* __restrict__ col,
                             unsigned short* __restrict__ out, int n) {
  int wv = (blockIdx.x * TPB + threadIdx.x) >> 6;
  int lane = threadIdx.x & 63;
  int li = lane & 15;
  int node = wv * 4 + (lane >> 4);
  if (node >= n) return;
  int s0 = off[node], s1 = off[node + 1];
  int cnt = s1 - s0;

  float a0 = 0.f, a1 = 0.f, a2 = 0.f, a3 = 0.f,
        a4 = 0.f, a5 = 0.f, a6 = 0.f, a7 = 0.f;

  for (int base = 0; base < cnt; base += 16) {
    int idx = s0 + base + li;
    int ci = col[min(idx, s1 - 1)];
    int lim = cnt - base;  // >0, group-uniform
#pragma unroll
    for (int j = 0; j < 16; ++j) {
      int c = __shfl(ci, j, 16);
      const uint4* p = (const uint4*)(X + (size_t)c * 128 + li * 8);
      uint4 v = *p;
      float s = (j < lim) ? 1.f : 0.f;
      a0 = fmaf(s, __uint_as_float(v.x << 16), a0);
      a1 = fmaf(s, __uint_as_float(v.x & 0xffff0000u), a1);
      a2 = fmaf(s, __uint_as_float(v.y << 16), a2);
      a3 = fmaf(s, __uint_as_float(v.y & 0xffff0000u), a3);
      a4 = fmaf(s, __uint_as_float(v.z << 16), a4);
      a5 = fmaf(s, __uint_as_float(v.z & 0xffff0000u), a5);
      a6 = fmaf(s, __uint_as_float(v.w << 16), a6);
      a7 = fmaf(s, __uint_as_float(v.w & 0xffff0000u), a7);
    }
  }

  float inv = (cnt > 0) ? 1.0f / (float)cnt : 0.f;
  uint4 o;
  o.x = ((unsigned int)f2bf(a1 * inv) << 16) | f2bf(a0 * inv);
  o.y = ((unsigned int)f2bf(a3 * inv) << 16) | f2bf(a2 * inv);
  o.z = ((unsigned int)f2bf(a5 * inv) << 16) | f2bf(a4 * inv);
  o.w = ((unsigned int)f2bf(a7 * inv) << 16) | f2bf(a6 * inv);
  *(uint4*)(out + (size_t)node * 128 + li * 8) = o;
}

// ---------------- layer-2 fused aggregate+add+ELU over P (64-dim, 128B rows) ----------
// mean commutes with W2l: out = elu(mean_j(P_j) + Q), P = h@W2l (bf16), Q = h@W2r+b2
// (f32). Rows are 128B -> 8 lanes x uint4; wave = 8 nodes; chunk of 8 edges.

__global__ void aggregate_add(const unsigned short* __restrict__ P,
                              const int* __restrict__ off, const int* __restrict__ col,
                              const float* __restrict__ Q, float* __restrict__ out, int n) {
  int wv = (blockIdx.x * TPB + threadIdx.x) >> 6;
  int lane = threadIdx.x & 63;
  int li = lane & 7;
  int node = wv * 8 + (lane >> 3);
  bool alive = node < n;
  int s0 = 0, s1 = 0;
  if (alive) { s0 = off[node]; s1 = off[node + 1]; }
  int cnt = s1 - s0;

  float a0 = 0.f, a1 = 0.f, a2 = 0.f, a3 = 0.f,
        a4 = 0.f, a5 = 0.f, a6 = 0.f, a7 = 0.f;

  for (int base = 0; base < cnt; base += 8) {
    int ci = col[max(0, min(s0 + base + li, s1 - 1))];
    int lim = cnt - base;
#pragma unroll
    for (int j = 0; j < 8; ++j) {
      int c = __shfl(ci, j, 8);
      uint4 v = *(const uint4*)(P + (size_t)c * 64 + li * 8);
      float s = (j < lim) ? 1.f : 0.f;
      a0 = fmaf(s, __uint_as_float(v.x << 16), a0);
      a1 = fmaf(s, __uint_as_float(v.x & 0xffff0000u), a1);
      a2 = fmaf(s, __uint_as_float(v.y << 16), a2);
      a3 = fmaf(s, __uint_as_float(v.y & 0xffff0000u), a3);
      a4 = fmaf(s, __uint_as_float(v.z << 16), a4);
      a5 = fmaf(s, __uint_as_float(v.z & 0xffff0000u), a5);
      a6 = fmaf(s, __uint_as_float(v.w << 16), a6);
      a7 = fmaf(s, __uint_as_float(v.w & 0xffff0000u), a7);
    }
  }

  if (alive) {
    float inv = (cnt > 0) ? 1.0f / (float)cnt : 0.f;
    const float4* qp = (const float4*)(Q + (size_t)node * 64 + li * 8);
    float4 q0 = qp[0], q1 = qp[1];
    float4 o0, o1;
    o0.x = a0 * inv + q0.x; o0.y = a1 * inv + q0.y;
    o0.z = a2 * inv + q0.z; o0.w = a3 * inv + q0.w;
    o1.x = a4 * inv + q1.x; o1.y = a5 * inv + q1.y;
    o1.z = a6 * inv + q1.z; o1.w = a7 * inv + q1.w;
    o0.x = (o0.x > 0.f) ? o0.x : expm1f(o0.x);
    o0.y = (o0.y > 0.f) ? o0.y : expm1f(o0.y);
    o0.z = (o0.z > 0.f) ? o0.z : expm1f(o0.z);
    o0.w = (o0.w > 0.f) ? o0.w : expm1f(o0.w);
    o1.x = (o1.x > 0.f) ? o1.x : expm1f(o1.x);
    o1.y = (o1.y > 0.f) ? o1.y : expm1f(o1.y);
    o1.z = (o1.z > 0.f) ? o1.z : expm1f(o1.z);
    o1.w = (o1.w > 0.f) ? o1.w : expm1f(o1.w);
    float4* op = (float4*)(out + (size_t)node * 64 + li * 8);
    op[0] = o0; op[1] = o1;
  }
}

// ---------------- MFMA GEMM: 128x128 tile, BK=32, counted-vmcnt double-buffer --------
// One block computes ALL 128 output cols -> A staged ONCE (the R3 y-split
// double-fetched A: 2x51MB gemm1 / 2x26MB gemm2, different XCDs -> L2 miss).
// BK=32 keeps LDS at 2*(128x32)*2B*2 = 32KB -> 4 blocks/CU resident.
// NCH = K/32 chunks (gemm1: 8, first 4 from A1/agg, last 4 from A2/x;
// gemm2': 4, all from A1/h). Pipeline: issue c0,c1; per chunk waitvm(4),
// barrier, 4 a-frags + 4 b-frags + 16 MFMA, lgkmcnt(0)+barrier, issue c+2.
// Swizzle for 64B rows: chunk cg = sc4 ^ ((row>>1)&3) -> residual 2-way bank
// aliasing (free, m136). MODE 0: ELU+dropout -> bf16[row][128] (layer 1).
// MODE 1: col<64 -> P bf16[row][64], col>=64 -> Q=v+bias f32[row][64].

template <int NCH, int MODE>
__global__ __launch_bounds__(256) void gemm_mfma(
    const unsigned short* __restrict__ A1, const unsigned short* __restrict__ A2,
    const unsigned short* __restrict__ Wt, const float* __restrict__ bias,
    const unsigned char* __restrict__ dmask, unsigned short* __restrict__ outb,
    float* __restrict__ outf, int n) {
  constexpr int IPC = 4;      // DMA issues per thread per chunk: 2 A + 2 B
  constexpr int KTOT = NCH * 32;
  __shared__ __align__(16) unsigned short sA[2][128 * 32];
  __shared__ __align__(16) unsigned short sB[2][128 * 32];

  int tid = threadIdx.x;
  int row0 = blockIdx.x * 128;
  int lane = tid & 63;
  int wid = tid >> 6;
  int wm = wid >> 1, wn = wid & 1;
  int lq = lane & 15, q = lane >> 4;

  int sr = tid >> 2, sc4 = tid & 3;          // staging slot: row sr (+t*64), 16B-chunk sc4
  int cg = sc4 ^ ((sr >> 1) & 3);            // global chunk this lane fetches (XOR swizzle)
                                             // ((sr+t*64)>>1)&3 == (sr>>1)&3, t*64 even*32

  // clamped A rows for the 2 staging sub-tiles (chunk-invariant)
  int arow[2];
#pragma unroll
  for (int t = 0; t < 2; ++t) arow[t] = min(row0 + sr + t * 64, n - 1);

  f32x4 acc[4][4];
#pragma unroll
  for (int i = 0; i < 4; ++i)
#pragma unroll
    for (int j = 0; j < 4; ++j) acc[i][j] = (f32x4)(0.f);

  // issue all DMA for chunk c into buffer b (IPC insts per thread)
  auto issue = [&](int c, int b) {
    const unsigned short* Asrc = (MODE == 0 && c >= NCH / 2) ? A2 : A1;
    int koff = (MODE == 0 ? (c & (NCH / 2 - 1)) : c) * 32;
#pragma unroll
    for (int t = 0; t < 2; ++t) {
      gload16(Asrc + (size_t)arow[t] * 128 + koff + cg * 8,
              (char*)sA[b] + t * 4096 + wid * 1024);
    }
#pragma unroll
    for (int t = 0; t < 2; ++t) {
      gload16(Wt + (size_t)(sr + t * 64) * KTOT + c * 32 + cg * 8,
              (char*)sB[b] + t * 4096 + wid * 1024);
    }
  };

  issue(0, 0);
  issue(1, 1);

#pragma unroll
  for (int c = 0; c < NCH; ++c) {
    // wait: current chunk's IPC loads landed; next chunk's may stay in flight
    if (c < NCH - 1) waitvm<IPC>(); else waitvm<0>();
    __builtin_amdgcn_s_barrier();
    __builtin_amdgcn_sched_barrier(0);

    const int buf = c & 1;
    bf16x8 a[4], b[4];
#pragma unroll
    for (int i = 0; i < 4; ++i) {
      int rr = wm * 64 + i * 16 + lq;
      a[i] = *(const bf16x8*)(&sA[buf][rr * 32 + ((q ^ ((rr >> 1) & 3)) * 8)]);
    }
#pragma unroll
    for (int j = 0; j < 4; ++j) {
      int rb = wn * 64 + j * 16 + lq;
      b[j] = *(const bf16x8*)(&sB[buf][rb * 32 + ((q ^ ((rb >> 1) & 3)) * 8)]);
    }
#pragma unroll
    for (int i = 0; i < 4; ++i)
#pragma unroll
      for (int j = 0; j < 4; ++j)
        acc[i][j] = __builtin_amdgcn_mfma_f32_16x16x32_bf16(a[i], b[j], acc[i][j], 0, 0, 0);

    if (c < NCH - 2) {
      // all fragment ds_reads serviced before anyone overwrites this buffer
      asm volatile("s_waitcnt lgkmcnt(0)" ::: "memory");
      __builtin_amdgcn_sched_barrier(0);
      __builtin_amdgcn_s_barrier();
      issue(c + 2, buf);
    }
  }

#pragma unroll
  for (int j = 0; j < 4; ++j) {
    int gcol = wn * 64 + j * 16 + lq;
    float bv;
    if (MODE == 0) bv = bias[gcol];
    else bv = (gcol >= 64) ? bias[gcol - 64] : 0.f;
#pragma unroll
    for (int i = 0; i < 4; ++i) {
      int rbase = row0 + wm * 64 + i * 16 + q * 4;
#pragma unroll
      for (int r = 0; r < 4; ++r) {
        int row = rbase + r;
        if (row >= n) continue;
        float v = acc[i][j][r] + bv;
        if (MODE == 0) {
          v = (v > 0.f) ? v : expm1f(v);
          unsigned char k = dmask[(size_t)row * 128 + gcol];
          v = k ? v * 1.25f : 0.f;
          outb[(size_t)row * 128 + gcol] = f2bf(v);
        } else {
          if (gcol < 64) outb[(size_t)row * 64 + gcol] = f2bf(v);
          else outf[(size_t)row * 64 + (gcol - 64)] = v;
        }
      }
    }
  }
}

// ---------------- launch ----------------

extern "C" void kernel_launch(void* const* d_in, const int* in_sizes, int n_in,
                              void* d_out, int out_size, void* d_ws, size_t ws_size,
                              hipStream_t stream) {
  const float* x = (const float*)d_in[0];
  const int* ei = (const int*)d_in[1];
  const float* dropu = (const float*)d_in[2];
  const float* W1l = (const float*)d_in[3];
  const float* W1r = (const float*)d_in[4];
  const float* b1 = (const float*)d_in[5];
  const float* W2l = (const float*)d_in[6];
  const float* W2r = (const float*)d_in[7];
  const float* b2 = (const float*)d_in[8];

  int n = in_sizes[0] / 128;
  int e = in_sizes[1] / 2;
  const int* src = ei;
  const int* dst = ei + e;
  float* out = (float*)d_out;

  char* w = (char*)d_ws;
  auto alloc = [&](size_t bytes) -> char* {
    char* p = w;
    w += (bytes + 255) & ~(size_t)255;
    return p;
  };
  int nbk = (n + 127) / 128;  // buckets of 128 nodes (782)
  int* off = (int*)alloc((size_t)(n + 1) * sizeof(int));
  int* col = (int*)alloc((size_t)e * sizeof(int));
  int* bcnt = (int*)alloc((size_t)nbk * sizeof(int));
  int* bbase = (int*)alloc((size_t)nbk * sizeof(int));
  unsigned short* xb = (unsigned short*)alloc((size_t)n * 128 * 2);
  unsigned short* hb = (unsigned short*)alloc((size_t)n * 128 * 2);
  unsigned short* aggb = (unsigned short*)alloc((size_t)n * 128 * 2);
  unsigned char* dmask = (unsigned char*)alloc((size_t)n * 128);
  unsigned short* Wt1 = (unsigned short*)alloc(128 * 256 * 2);
  unsigned short* Wt2 = (unsigned short*)alloc(128 * 128 * 2);
  // overlays (stream-ordered lifetimes):
  //   be (8.0MB)  -> aggb region: dead before agg1 writes aggb
  //   pb (12.8MB) -> xb region:   xb dead after gemm1 (A2 input)
  //   qf (25.6MB) -> aggb region: aggb dead after gemm1 (A1 input)
  unsigned int* be = (unsigned int*)aggb;
  unsigned short* pb = xb;
  float* qf = (float*)aggb;

  hipMemsetAsync(bcnt, 0, (size_t)nbk * sizeof(int), stream);

  int gMS = (e + EPB - 1) / EPB;
  multisplit_scatter<<<gMS, TPB, 0, stream>>>(src, dst, be, bcnt, e, nbk);
  bucket_scan<<<1, TPB, 0, stream>>>(bcnt, bbase, nbk);
  per_bucket_build<<<nbk, TPB, 0, stream>>>(be, bcnt, bbase, off, col, n, e);

  int n4 = n * 128 / 4;
  f32_to_bf16_v4<<<(n4 + TPB - 1) / TPB, TPB, 0, stream>>>(x, xb, n4);
  make_dropmask<<<(n4 + TPB - 1) / TPB, TPB, 0, stream>>>(dropu, dmask, n4);
  build_wt<128><<<(128 * 256 + TPB - 1) / TPB, TPB, 0, stream>>>(W1l, W1r, Wt1);
  build_wt2p<<<(128 * 128 + TPB - 1) / TPB, TPB, 0, stream>>>(W2l, W2r, Wt2);

  int gAgg1 = ((n + 3) / 4 * 64 + TPB - 1) / TPB;  // 16 lanes/node, 4 nodes/wave
  int gAgg2 = (n + 31) / 32;                       // 8 lanes/node, 8 nodes/wave
  int gR = (n + 127) / 128;

  // layer 1: agg(x) -> gemm (K=256: [agg|x]) -> elu+drop -> hb
  aggregate_bf<<<gAgg1, TPB, 0, stream>>>(xb, off, col, aggb, n);
  gemm_mfma<8, 0><<<gR, TPB, 0, stream>>>(aggb, xb, Wt1, b1, dmask, hb, nullptr, n);

  // layer 2 (mean commuted with W2l): P=h@W2l (bf16), Q=h@W2r+b2 (f32),
  // out = elu(mean_j P_j + Q)
  gemm_mfma<4, 1><<<gR, TPB, 0, stream>>>(hb, nullptr, Wt2, b2, nullptr, pb, qf, n);
  aggregate_add<<<gAgg2, TPB, 0, stream>>>(pb, off, col, qf, out, n);
}

// Round 8
// 404.307 us; speedup vs baseline: 1.0614x; 1.0614x over previous
//
#include <hip/hip_runtime.h>
#include <cstdint>
#include <cstddef>

#define TPB 256
#define BCAP 2560      // bucket capacity: mean 2046, sigma ~45 -> 11 sigma headroom
#define NBKMAX 800     // max buckets in LDS (n=100k -> 782)
#define EPB 8192       // edges per multisplit block

typedef short bf16x8 __attribute__((ext_vector_type(8)));
typedef float f32x4 __attribute__((ext_vector_type(4)));

__device__ __forceinline__ unsigned short f2bf(float f) {
  unsigned int u = __float_as_uint(f);
  unsigned int r = (u + 0x7fffu + ((u >> 16) & 1u)) >> 16;  // RNE
  return (unsigned short)r;
}
__device__ __forceinline__ float bf2f(unsigned short h) {
  return __uint_as_float(((unsigned int)h) << 16);
}

// async 16B global->LDS DMA. LDS dest is wave-uniform base + lane*16.
__device__ __forceinline__ void gload16(const void* g, void* l) {
  __builtin_amdgcn_global_load_lds(
      (const __attribute__((address_space(1))) unsigned int*)g,
      (__attribute__((address_space(3))) unsigned int*)l, 16, 0, 0);
}

// counted vmcnt wait: wait until <= N vector-memory ops outstanding.
template <int N>
__device__ __forceinline__ void waitvm() {
  asm volatile("s_waitcnt vmcnt(%0)" ::"n"(N) : "memory");
}

// ---------------- bucketed CSR build (multisplit, R4-proven) ----------------

__global__ __launch_bounds__(256) void multisplit_scatter(
    const int* __restrict__ src, const int* __restrict__ dst,
    unsigned int* __restrict__ be, int* __restrict__ bcnt, int e, int nbk) {
  __shared__ int hist[NBKMAX];
  __shared__ int curs[NBKMAX];
  int tx = threadIdx.x;
  int e0 = blockIdx.x * EPB;
  int e1 = min(e, e0 + EPB);

  for (int b = tx; b < nbk; b += TPB) hist[b] = 0;
  __syncthreads();
  for (int i = e0 + tx; i < e1; i += TPB) atomicAdd(&hist[dst[i] >> 7], 1);
  __syncthreads();
  int rot = (blockIdx.x * 131) % nbk;
  for (int s = tx; s < nbk; s += TPB) {
    int b = s + rot;
    if (b >= nbk) b -= nbk;
    int h = hist[b];
    curs[b] = (h > 0) ? atomicAdd(&bcnt[b], h) : 0;
  }
  __syncthreads();
  for (int i = e0 + tx; i < e1; i += TPB) {
    int d = dst[i];
    int b = d >> 7;
    int p = atomicAdd(&curs[b], 1);
    if (p < BCAP)
      be[(size_t)b * BCAP + p] = ((unsigned int)(d & 127) << 17) | (unsigned int)src[i];
  }
}

__global__ void bucket_scan(const int* __restrict__ bcnt, int* __restrict__ bbase, int nbk) {
  __shared__ int s[TPB];
  __shared__ int carry;
  int tx = threadIdx.x;
  if (tx == 0) carry = 0;
  __syncthreads();
  for (int base = 0; base < nbk; base += TPB) {
    int i = base + tx;
    int v = (i < nbk) ? bcnt[i] : 0;
    s[tx] = v;
    __syncthreads();
    for (int d = 1; d < TPB; d <<= 1) {
      int t = (tx >= d) ? s[tx - d] : 0;
      __syncthreads();
      s[tx] += t;
      __syncthreads();
    }
    int c = carry;
    if (i < nbk) bbase[i] = c + s[tx] - v;
    __syncthreads();
    if (tx == TPB - 1) carry = c + s[tx];
    __syncthreads();
  }
}

__global__ __launch_bounds__(256) void per_bucket_build(
    const unsigned int* __restrict__ be, const int* __restrict__ bcnt,
    const int* __restrict__ bbase, int* __restrict__ off, int* __restrict__ col,
    int n, int e) {
  int b = blockIdx.x, tx = threadIdx.x;
  int cnt = bcnt[b];
  if (cnt > BCAP) cnt = BCAP;
  int base = bbase[b];
  int node0 = b << 7;
  __shared__ int scnt[128];
  __shared__ int sscan[128];
  if (tx < 128) scnt[tx] = 0;
  __syncthreads();
  const unsigned int* eb = be + (size_t)b * BCAP;
  for (int i = tx; i < cnt; i += 256) atomicAdd(&scnt[eb[i] >> 17], 1);
  __syncthreads();
  if (tx < 128) sscan[tx] = scnt[tx];
  __syncthreads();
  for (int d = 1; d < 128; d <<= 1) {
    int t = 0;
    if (tx < 128 && tx >= d) t = sscan[tx - d];
    __syncthreads();
    if (tx < 128) sscan[tx] += t;
    __syncthreads();
  }
  if (tx < 128) {
    int excl = sscan[tx] - scnt[tx];
    if (node0 + tx < n) off[node0 + tx] = base + excl;
    scnt[tx] = excl;  // becomes fill cursor
  }
  if (b == 0 && tx == 0) off[n] = e;
  __syncthreads();
  for (int i = tx; i < cnt; i += 256) {
    unsigned int u = eb[i];
    int p = atomicAdd(&scnt[u >> 17], 1);
    col[base + p] = (int)(u & 0x1ffff);
  }
}

// ---------------- converts ----------------

__global__ void f32_to_bf16_v4(const float* __restrict__ in, unsigned short* __restrict__ out,
                               int n4) {
  int i = blockIdx.x * TPB + threadIdx.x;
  if (i >= n4) return;
  float4 v = ((const float4*)in)[i];
  ushort4 o;
  o.x = f2bf(v.x); o.y = f2bf(v.y); o.z = f2bf(v.z); o.w = f2bf(v.w);
  ((ushort4*)out)[i] = o;
}

__global__ void make_dropmask(const float* __restrict__ u, unsigned char* __restrict__ m,
                              int n4) {
  int i = blockIdx.x * TPB + threadIdx.x;
  if (i >= n4) return;
  float4 v = ((const float4*)u)[i];
  uchar4 o;
  o.x = (v.x >= 0.2f) ? 1 : 0;
  o.y = (v.y >= 0.2f) ? 1 : 0;
  o.z = (v.z >= 0.2f) ? 1 : 0;
  o.w = (v.w >= 0.2f) ? 1 : 0;
  ((uchar4*)m)[i] = o;
}

// layer-1 weights: Wt1[128 out][256 K] = concat(W1l;W1r) transposed
template <int NF>
__global__ void build_wt(const float* __restrict__ Wl, const float* __restrict__ Wr,
                         unsigned short* __restrict__ Wt) {
  int idx = blockIdx.x * TPB + threadIdx.x;
  if (idx >= NF * 256) return;
  int nn = idx >> 8;
  int k = idx & 255;
  float v = (k < 128) ? Wl[k * NF + nn] : Wr[(k - 128) * NF + nn];
  Wt[idx] = f2bf(v);
}

// layer-2' weights: Wt2[128 out][128 K]; rows 0-63 = W2l^T (-> P), 64-127 = W2r^T (-> Q)
__global__ void build_wt2p(const float* __restrict__ W2l, const float* __restrict__ W2r,
                           unsigned short* __restrict__ Wt) {
  int idx = blockIdx.x * TPB + threadIdx.x;
  if (idx >= 128 * 128) return;
  int nn = idx >> 7;
  int k = idx & 127;
  float v = (nn < 64) ? W2l[k * 64 + nn] : W2r[k * 64 + (nn - 64)];
  Wt[idx] = f2bf(v);
}

// ---------------- layer-1 mean aggregation: 16 lanes per node (R3-proven) ----------
// One wave = 4 nodes. Per chunk of 16 edges, lane li preloads col[s0+base+li]
// (clamped to s1-1), then 16 unrolled iterations broadcast c via shfl(width=16)
// and gather uint4 at X + c*128 + li*8. Stable at 66us / 177MB FETCH / 3.1TB/s
// across 4 rewrites -> treated as the random-gather floor. R5's 2-node
// interleave SPILLED (VGPR pressure); do not widen without resource check.

__global__ void aggregate_bf(const unsigned short* __restrict__ X,
                             const int* __restrict__ off, const int* __restrict__ col,
                             unsigned short* __restrict__ out, int n) {
  int wv = (blockIdx.x * TPB + threadIdx.x) >> 6;
  int lane = threadIdx.x & 63;
  int li = lane & 15;
  int node = wv * 4 + (lane >> 4);
  if (node >= n) return;
  int s0 = off[node], s1 = off[node + 1];
  int cnt = s1 - s0;

  float a0 = 0.f, a1 = 0.f, a2 = 0.f, a3 = 0.f,
        a4 = 0.f, a5 = 0.f, a6 = 0.f, a7 = 0.f;

  for (int base = 0; base < cnt; base += 16) {
    int idx = s0 + base + li;
    int ci = col[min(idx, s1 - 1)];
    int lim = cnt - base;  // >0, group-uniform
#pragma unroll
    for (int j = 0; j < 16; ++j) {
      int c = __shfl(ci, j, 16);
      const uint4* p = (const uint4*)(X + (size_t)c * 128 + li * 8);
      uint4 v = *p;
      float s = (j < lim) ? 1.f : 0.f;
      a0 = fmaf(s, __uint_as_float(v.x << 16), a0);
      a1 = fmaf(s, __uint_as_float(v.x & 0xffff0000u), a1);
      a2 = fmaf(s, __uint_as_float(v.y << 16), a2);
      a3 = fmaf(s, __uint_as_float(v.y & 0xffff0000u), a3);
      a4 = fmaf(s, __uint_as_float(v.z << 16), a4);
      a5 = fmaf(s, __uint_as_float(v.z & 0xffff0000u), a5);
      a6 = fmaf(s, __uint_as_float(v.w << 16), a6);
      a7 = fmaf(s, __uint_as_float(v.w & 0xffff0000u), a7);
    }
  }

  float inv = (cnt > 0) ? 1.0f / (float)cnt : 0.f;
  uint4 o;
  o.x = ((unsigned int)f2bf(a1 * inv) << 16) | f2bf(a0 * inv);
  o.y = ((unsigned int)f2bf(a3 * inv) << 16) | f2bf(a2 * inv);
  o.z = ((unsigned int)f2bf(a5 * inv) << 16) | f2bf(a4 * inv);
  o.w = ((unsigned int)f2bf(a7 * inv) << 16) | f2bf(a6 * inv);
  *(uint4*)(out + (size_t)node * 128 + li * 8) = o;
}

// ---------------- layer-2 fused aggregate+add+ELU over P (64-dim, 128B rows) ----------
// mean commutes with W2l: out = elu(mean_j(P_j) + Q), P = h@W2l (bf16), Q = h@W2r+b2
// (f32). Rows are 128B -> 8 lanes x uint4; wave = 8 nodes; chunk of 8 edges.

__global__ void aggregate_add(const unsigned short* __restrict__ P,
                              const int* __restrict__ off, const int* __restrict__ col,
                              const float* __restrict__ Q, float* __restrict__ out, int n) {
  int wv = (blockIdx.x * TPB + threadIdx.x) >> 6;
  int lane = threadIdx.x & 63;
  int li = lane & 7;
  int node = wv * 8 + (lane >> 3);
  bool alive = node < n;
  int s0 = 0, s1 = 0;
  if (alive) { s0 = off[node]; s1 = off[node + 1]; }
  int cnt = s1 - s0;

  float a0 = 0.f, a1 = 0.f, a2 = 0.f, a3 = 0.f,
        a4 = 0.f, a5 = 0.f, a6 = 0.f, a7 = 0.f;

  for (int base = 0; base < cnt; base += 8) {
    int ci = col[max(0, min(s0 + base + li, s1 - 1))];
    int lim = cnt - base;
#pragma unroll
    for (int j = 0; j < 8; ++j) {
      int c = __shfl(ci, j, 8);
      uint4 v = *(const uint4*)(P + (size_t)c * 64 + li * 8);
      float s = (j < lim) ? 1.f : 0.f;
      a0 = fmaf(s, __uint_as_float(v.x << 16), a0);
      a1 = fmaf(s, __uint_as_float(v.x & 0xffff0000u), a1);
      a2 = fmaf(s, __uint_as_float(v.y << 16), a2);
      a3 = fmaf(s, __uint_as_float(v.y & 0xffff0000u), a3);
      a4 = fmaf(s, __uint_as_float(v.z << 16), a4);
      a5 = fmaf(s, __uint_as_float(v.z & 0xffff0000u), a5);
      a6 = fmaf(s, __uint_as_float(v.w << 16), a6);
      a7 = fmaf(s, __uint_as_float(v.w & 0xffff0000u), a7);
    }
  }

  if (alive) {
    float inv = (cnt > 0) ? 1.0f / (float)cnt : 0.f;
    const float4* qp = (const float4*)(Q + (size_t)node * 64 + li * 8);
    float4 q0 = qp[0], q1 = qp[1];
    float4 o0, o1;
    o0.x = a0 * inv + q0.x; o0.y = a1 * inv + q0.y;
    o0.z = a2 * inv + q0.z; o0.w = a3 * inv + q0.w;
    o1.x = a4 * inv + q1.x; o1.y = a5 * inv + q1.y;
    o1.z = a6 * inv + q1.z; o1.w = a7 * inv + q1.w;
    o0.x = (o0.x > 0.f) ? o0.x : expm1f(o0.x);
    o0.y = (o0.y > 0.f) ? o0.y : expm1f(o0.y);
    o0.z = (o0.z > 0.f) ? o0.z : expm1f(o0.z);
    o0.w = (o0.w > 0.f) ? o0.w : expm1f(o0.w);
    o1.x = (o1.x > 0.f) ? o1.x : expm1f(o1.x);
    o1.y = (o1.y > 0.f) ? o1.y : expm1f(o1.y);
    o1.z = (o1.z > 0.f) ? o1.z : expm1f(o1.z);
    o1.w = (o1.w > 0.f) ? o1.w : expm1f(o1.w);
    float4* op = (float4*)(out + (size_t)node * 64 + li * 8);
    op[0] = o0; op[1] = o1;
  }
}

// ---------------- MFMA GEMM: 128x64 blocks, counted-vmcnt double-buffer ----------------
// R6 structure (grid 1564 eq., 48KB LDS, 3 blocks/CU) + XCD pair co-location:
// pair p = row-block, y in {0,1} = 64-col slab. Decode g -> (p,y) so both
// members of a pair are congruent mod 8 -> same XCD (round-robin dispatch),
// making the duplicated A-stage an L2 hit (R6 had them 782 slots apart ->
// cross-XCD, L3 latency ~600cy vs L2 ~200cy). R7 lesson: grid >= ~6 blk/CU
// beats traffic dedup (128x128 BK=32 grid-782 regressed to 76us, FETCH UP).
// NCH = K/64 chunks. MODE 0: ELU+dropout -> bf16[row][128] (layer 1).
// MODE 1: gcol<64 -> P bf16[row][64], gcol>=64 -> Q=v+bias f32[row][64].
// Pipeline: issue c0,c1; per chunk waitvm(6), barrier, compute,
// lgkmcnt(0)+barrier, issue c+2 into freed buffer.

template <int NCH, int MODE>
__global__ __launch_bounds__(256) void gemm_mfma(
    const unsigned short* __restrict__ A1, const unsigned short* __restrict__ A2,
    const unsigned short* __restrict__ Wt, const float* __restrict__ bias,
    const unsigned char* __restrict__ dmask, unsigned short* __restrict__ outb,
    float* __restrict__ outf, int n) {
  constexpr int IPC = 6;      // DMA issues per thread per chunk: 4 A + 2 B
  constexpr int KTOT = NCH * 64;
  __shared__ __align__(16) unsigned short sA[2][128 * 64];
  __shared__ __align__(16) unsigned short sB[2][64 * 64];

  // XCD pair co-location decode: g = (p>>3)*16 + y*8 + (p&7)
  int g = blockIdx.x;
  int p = (g >> 4) * 8 + (g & 7);
  int yy = (g >> 3) & 1;
  int nrb = (n + 127) >> 7;
  if (p >= nrb) return;  // uniform for whole block; no barrier executed yet

  int tid = threadIdx.x;
  int row0 = p * 128;
  int ncol0 = yy * 64;
  int lane = tid & 63;
  int wid = tid >> 6;
  int wm = wid >> 1, wn = wid & 1;
  int lq = lane & 15, q = lane >> 4;

  int sr = tid >> 3, sc8 = tid & 7;          // staging slot: row sr (+t*32), chunk sc8
  int cg = sc8 ^ (sr & 7);                   // global chunk this lane fetches (XOR swizzle)

  // clamped A rows for the 4 staging sub-tiles (chunk-invariant)
  int arow[4];
#pragma unroll
  for (int t = 0; t < 4; ++t) arow[t] = min(row0 + sr + t * 32, n - 1);

  f32x4 acc[4][2];
#pragma unroll
  for (int i = 0; i < 4; ++i)
#pragma unroll
    for (int j = 0; j < 2; ++j) acc[i][j] = (f32x4)(0.f);

  // issue all DMA for chunk c into buffer b (IPC insts per thread)
  auto issue = [&](int c, int b) {
    const unsigned short* Asrc = (c < 2) ? A1 : A2;
    int koff = (c & 1) * 64;
#pragma unroll
    for (int t = 0; t < 4; ++t) {
      gload16(Asrc + (size_t)arow[t] * 128 + koff + cg * 8,
              (char*)sA[b] + t * 4096 + wid * 1024);
    }
#pragma unroll
    for (int t = 0; t < 2; ++t) {
      gload16(Wt + (size_t)(ncol0 + sr + t * 32) * KTOT + c * 64 + cg * 8,
              (char*)sB[b] + t * 4096 + wid * 1024);
    }
  };

  issue(0, 0);
  issue(1, 1);

#pragma unroll
  for (int c = 0; c < NCH; ++c) {
    // wait: current chunk's IPC loads landed; next chunk's may stay in flight
    if (c < NCH - 1) waitvm<IPC>(); else waitvm<0>();
    __builtin_amdgcn_s_barrier();
    __builtin_amdgcn_sched_barrier(0);

    const int buf = c & 1;
#pragma unroll
    for (int ks = 0; ks < 2; ++ks) {
      bf16x8 a[4], b[2];
#pragma unroll
      for (int i = 0; i < 4; ++i) {
        int rr = wm * 64 + i * 16 + lq;
        a[i] = *(const bf16x8*)(&sA[buf][rr * 64 + (((ks * 4 + q) ^ (rr & 7)) * 8)]);
      }
#pragma unroll
      for (int j = 0; j < 2; ++j) {
        int rb = wn * 32 + j * 16 + lq;
        b[j] = *(const bf16x8*)(&sB[buf][rb * 64 + (((ks * 4 + q) ^ (rb & 7)) * 8)]);
      }
#pragma unroll
      for (int i = 0; i < 4; ++i)
#pragma unroll
        for (int j = 0; j < 2; ++j)
          acc[i][j] = __builtin_amdgcn_mfma_f32_16x16x32_bf16(a[i], b[j], acc[i][j], 0, 0, 0);
    }

    if (c < NCH - 2) {
      // all fragment ds_reads serviced before anyone overwrites this buffer
      asm volatile("s_waitcnt lgkmcnt(0)" ::: "memory");
      __builtin_amdgcn_sched_barrier(0);
      __builtin_amdgcn_s_barrier();
      issue(c + 2, buf);
    }
  }

#pragma unroll
  for (int j = 0; j < 2; ++j) {
    int gcol = ncol0 + wn * 32 + j * 16 + lq;
    float bv;
    if (MODE == 0) bv = bias[gcol];
    else bv = (gcol >= 64) ? bias[gcol - 64] : 0.f;
#pragma unroll
    for (int i = 0; i < 4; ++i) {
      int rbase = row0 + wm * 64 + i * 16 + q * 4;
#pragma unroll
      for (int r = 0; r < 4; ++r) {
        int row = rbase + r;
        if (row >= n) continue;
        float v = acc[i][j][r] + bv;
        if (MODE == 0) {
          v = (v > 0.f) ? v : expm1f(v);
          unsigned char k = dmask[(size_t)row * 128 + gcol];
          v = k ? v * 1.25f : 0.f;
          outb[(size_t)row * 128 + gcol] = f2bf(v);
        } else {
          if (gcol < 64) outb[(size_t)row * 64 + gcol] = f2bf(v);
          else outf[(size_t)row * 64 + (gcol - 64)] = v;
        }
      }
    }
  }
}

// ---------------- launch ----------------

extern "C" void kernel_launch(void* const* d_in, const int* in_sizes, int n_in,
                              void* d_out, int out_size, void* d_ws, size_t ws_size,
                              hipStream_t stream) {
  const float* x = (const float*)d_in[0];
  const int* ei = (const int*)d_in[1];
  const float* dropu = (const float*)d_in[2];
  const float* W1l = (const float*)d_in[3];
  const float* W1r = (const float*)d_in[4];
  const float* b1 = (const float*)d_in[5];
  const float* W2l = (const float*)d_in[6];
  const float* W2r = (const float*)d_in[7];
  const float* b2 = (const float*)d_in[8];

  int n = in_sizes[0] / 128;
  int e = in_sizes[1] / 2;
  const int* src = ei;
  const int* dst = ei + e;
  float* out = (float*)d_out;

  char* w = (char*)d_ws;
  auto alloc = [&](size_t bytes) -> char* {
    char* p = w;
    w += (bytes + 255) & ~(size_t)255;
    return p;
  };
  int nbk = (n + 127) / 128;  // buckets of 128 nodes (782)
  int* off = (int*)alloc((size_t)(n + 1) * sizeof(int));
  int* col = (int*)alloc((size_t)e * sizeof(int));
  int* bcnt = (int*)alloc((size_t)nbk * sizeof(int));
  int* bbase = (int*)alloc((size_t)nbk * sizeof(int));
  unsigned short* xb = (unsigned short*)alloc((size_t)n * 128 * 2);
  unsigned short* hb = (unsigned short*)alloc((size_t)n * 128 * 2);
  unsigned short* aggb = (unsigned short*)alloc((size_t)n * 128 * 2);
  unsigned char* dmask = (unsigned char*)alloc((size_t)n * 128);
  unsigned short* Wt1 = (unsigned short*)alloc(128 * 256 * 2);
  unsigned short* Wt2 = (unsigned short*)alloc(128 * 128 * 2);
  // overlays (stream-ordered lifetimes):
  //   be (8.0MB)  -> aggb region: dead before agg1 writes aggb
  //   pb (12.8MB) -> xb region:   xb dead after gemm1 (A2 input)
  //   qf (25.6MB) -> aggb region: aggb dead after gemm1 (A1 input)
  unsigned int* be = (unsigned int*)aggb;
  unsigned short* pb = xb;
  float* qf = (float*)aggb;

  hipMemsetAsync(bcnt, 0, (size_t)nbk * sizeof(int), stream);

  int gMS = (e + EPB - 1) / EPB;
  multisplit_scatter<<<gMS, TPB, 0, stream>>>(src, dst, be, bcnt, e, nbk);
  bucket_scan<<<1, TPB, 0, stream>>>(bcnt, bbase, nbk);
  per_bucket_build<<<nbk, TPB, 0, stream>>>(be, bcnt, bbase, off, col, n, e);

  int n4 = n * 128 / 4;
  f32_to_bf16_v4<<<(n4 + TPB - 1) / TPB, TPB, 0, stream>>>(x, xb, n4);
  make_dropmask<<<(n4 + TPB - 1) / TPB, TPB, 0, stream>>>(dropu, dmask, n4);
  build_wt<128><<<(128 * 256 + TPB - 1) / TPB, TPB, 0, stream>>>(W1l, W1r, Wt1);
  build_wt2p<<<(128 * 128 + TPB - 1) / TPB, TPB, 0, stream>>>(W2l, W2r, Wt2);

  int gAgg1 = ((n + 3) / 4 * 64 + TPB - 1) / TPB;  // 16 lanes/node, 4 nodes/wave
  int gAgg2 = (n + 31) / 32;                       // 8 lanes/node, 8 nodes/wave
  int gR = (n + 127) / 128;                        // 782 row-blocks
  int gG = ((gR + 7) / 8) * 16;                    // XCD-paired grid (1568)

  // layer 1: agg(x) -> gemm (K=256: [agg|x]) -> elu+drop -> hb
  aggregate_bf<<<gAgg1, TPB, 0, stream>>>(xb, off, col, aggb, n);
  gemm_mfma<4, 0><<<gG, TPB, 0, stream>>>(aggb, xb, Wt1, b1, dmask, hb, nullptr, n);

  // layer 2 (mean commuted with W2l): P=h@W2l (bf16), Q=h@W2r+b2 (f32),
  // out = elu(mean_j P_j + Q)
  gemm_mfma<2, 1><<<gG, TPB, 0, stream>>>(hb, nullptr, Wt2, b2, nullptr, pb, qf, n);
  aggregate_add<<<gAgg2, TPB, 0, stream>>>(pb, off, col, qf, out, n);
}

// Round 9
// 382.157 us; speedup vs baseline: 1.1229x; 1.0580x over previous
//
#include <hip/hip_runtime.h>
#include <cstdint>
#include <cstddef>

#define TPB 256
#define BCAP 2560      // bucket capacity: mean 2046, sigma ~45 -> 11 sigma headroom
#define NBKMAX 800     // max buckets in LDS (n=100k -> 782)
#define EPB 8192       // edges per multisplit block

typedef short bf16x8 __attribute__((ext_vector_type(8)));
typedef float f32x4 __attribute__((ext_vector_type(4)));

__device__ __forceinline__ unsigned short f2bf(float f) {
  unsigned int u = __float_as_uint(f);
  unsigned int r = (u + 0x7fffu + ((u >> 16) & 1u)) >> 16;  // RNE
  return (unsigned short)r;
}
__device__ __forceinline__ float bf2f(unsigned short h) {
  return __uint_as_float(((unsigned int)h) << 16);
}

// fast ELU negative branch: exp(v)-1 via hardware exp; |err| ~1e-4 absolute,
// well under the bf16 rounding already applied to every intermediate.
__device__ __forceinline__ float elu_neg(float v) { return __expf(v) - 1.0f; }

// async 16B global->LDS DMA. LDS dest is wave-uniform base + lane*16.
__device__ __forceinline__ void gload16(const void* g, void* l) {
  __builtin_amdgcn_global_load_lds(
      (const __attribute__((address_space(1))) unsigned int*)g,
      (__attribute__((address_space(3))) unsigned int*)l, 16, 0, 0);
}

// counted vmcnt wait: wait until <= N vector-memory ops outstanding.
template <int N>
__device__ __forceinline__ void waitvm() {
  asm volatile("s_waitcnt vmcnt(%0)" ::"n"(N) : "memory");
}

// ---------------- bucketed CSR build (multisplit; scan-free base alloc) ----------------

__global__ __launch_bounds__(256) void multisplit_scatter(
    const int* __restrict__ src, const int* __restrict__ dst,
    unsigned int* __restrict__ be, int* __restrict__ bcnt, int e, int nbk) {
  __shared__ int hist[NBKMAX];
  __shared__ int curs[NBKMAX];
  int tx = threadIdx.x;
  int e0 = blockIdx.x * EPB;
  int e1 = min(e, e0 + EPB);

  for (int b = tx; b < nbk; b += TPB) hist[b] = 0;
  __syncthreads();
  for (int i = e0 + tx; i < e1; i += TPB) atomicAdd(&hist[dst[i] >> 7], 1);
  __syncthreads();
  int rot = (blockIdx.x * 131) % nbk;
  for (int s = tx; s < nbk; s += TPB) {
    int b = s + rot;
    if (b >= nbk) b -= nbk;
    int h = hist[b];
    curs[b] = (h > 0) ? atomicAdd(&bcnt[b], h) : 0;
  }
  __syncthreads();
  for (int i = e0 + tx; i < e1; i += TPB) {
    int d = dst[i];
    int b = d >> 7;
    int p = atomicAdd(&curs[b], 1);
    if (p < BCAP)
      be[(size_t)b * BCAP + p] = ((unsigned int)(d & 127) << 17) | (unsigned int)src[i];
  }
}

// base allocation via global cursor (gcur) -> no prefix-scan kernel, no
// cross-bucket contiguity. Per-node extent published as off[] / offend[].
__global__ __launch_bounds__(256) void per_bucket_build(
    const unsigned int* __restrict__ be, const int* __restrict__ bcnt,
    int* __restrict__ gcur, int* __restrict__ off, int* __restrict__ offend,
    int* __restrict__ col, int n) {
  int b = blockIdx.x, tx = threadIdx.x;
  int cnt = bcnt[b];
  if (cnt > BCAP) cnt = BCAP;
  int node0 = b << 7;
  __shared__ int scnt[128];
  __shared__ int sscan[128];
  __shared__ int sbase;
  if (tx < 128) scnt[tx] = 0;
  __syncthreads();
  const unsigned int* eb = be + (size_t)b * BCAP;
  for (int i = tx; i < cnt; i += 256) atomicAdd(&scnt[eb[i] >> 17], 1);
  __syncthreads();
  if (tx < 128) sscan[tx] = scnt[tx];
  __syncthreads();
  for (int d = 1; d < 128; d <<= 1) {
    int t = 0;
    if (tx < 128 && tx >= d) t = sscan[tx - d];
    __syncthreads();
    if (tx < 128) sscan[tx] += t;
    __syncthreads();
  }
  if (tx == 0) sbase = atomicAdd(gcur, cnt);
  __syncthreads();
  int base = sbase;
  if (tx < 128) {
    int excl = sscan[tx] - scnt[tx];
    if (node0 + tx < n) {
      off[node0 + tx] = base + excl;
      offend[node0 + tx] = base + sscan[tx];
    }
    scnt[tx] = excl;  // becomes fill cursor
  }
  __syncthreads();
  for (int i = tx; i < cnt; i += 256) {
    unsigned int u = eb[i];
    int p = atomicAdd(&scnt[u >> 17], 1);
    col[base + p] = (int)(u & 0x1ffff);
  }
}

// ---------------- converts ----------------

__global__ void f32_to_bf16_v4(const float* __restrict__ in, unsigned short* __restrict__ out,
                               int n4) {
  int i = blockIdx.x * TPB + threadIdx.x;
  if (i >= n4) return;
  float4 v = ((const float4*)in)[i];
  ushort4 o;
  o.x = f2bf(v.x); o.y = f2bf(v.y); o.z = f2bf(v.z); o.w = f2bf(v.w);
  ((ushort4*)out)[i] = o;
}

__global__ void make_dropmask(const float* __restrict__ u, unsigned char* __restrict__ m,
                              int n4) {
  int i = blockIdx.x * TPB + threadIdx.x;
  if (i >= n4) return;
  float4 v = ((const float4*)u)[i];
  uchar4 o;
  o.x = (v.x >= 0.2f) ? 1 : 0;
  o.y = (v.y >= 0.2f) ? 1 : 0;
  o.z = (v.z >= 0.2f) ? 1 : 0;
  o.w = (v.w >= 0.2f) ? 1 : 0;
  ((uchar4*)m)[i] = o;
}

// layer-1 weights: Wt1[128 out][256 K] = concat(W1l;W1r) transposed
template <int NF>
__global__ void build_wt(const float* __restrict__ Wl, const float* __restrict__ Wr,
                         unsigned short* __restrict__ Wt) {
  int idx = blockIdx.x * TPB + threadIdx.x;
  if (idx >= NF * 256) return;
  int nn = idx >> 8;
  int k = idx & 255;
  float v = (k < 128) ? Wl[k * NF + nn] : Wr[(k - 128) * NF + nn];
  Wt[idx] = f2bf(v);
}

// layer-2' weights: Wt2[128 out][128 K]; rows 0-63 = W2l^T (-> P), 64-127 = W2r^T (-> Q)
__global__ void build_wt2p(const float* __restrict__ W2l, const float* __restrict__ W2r,
                           unsigned short* __restrict__ Wt) {
  int idx = blockIdx.x * TPB + threadIdx.x;
  if (idx >= 128 * 128) return;
  int nn = idx >> 7;
  int k = idx & 127;
  float v = (nn < 64) ? W2l[k * 64 + nn] : W2r[k * 64 + (nn - 64)];
  Wt[idx] = f2bf(v);
}

// ---------------- layer-1 mean aggregation: 16 lanes per node (R3-proven) ----------
// One wave = 4 nodes. Stable at 66us / 177MB FETCH / 3.1TB/s across 4 rewrites
// -> treated as the random-gather floor. R5's 2-node interleave SPILLED.

__global__ void aggregate_bf(const unsigned short* __restrict__ X,
                             const int* __restrict__ off, const int* __restrict__ offend,
                             const int* __restrict__ col,
                             unsigned short* __restrict__ out, int n) {
  int wv = (blockIdx.x * TPB + threadIdx.x) >> 6;
  int lane = threadIdx.x & 63;
  int li = lane & 15;
  int node = wv * 4 + (lane >> 4);
  if (node >= n) return;
  int s0 = off[node], s1 = offend[node];
  int cnt = s1 - s0;

  float a0 = 0.f, a1 = 0.f, a2 = 0.f, a3 = 0.f,
        a4 = 0.f, a5 = 0.f, a6 = 0.f, a7 = 0.f;

  for (int base = 0; base < cnt; base += 16) {
    int idx = s0 + base + li;
    int ci = col[min(idx, s1 - 1)];
    int lim = cnt - base;  // >0, group-uniform
#pragma unroll
    for (int j = 0; j < 16; ++j) {
      int c = __shfl(ci, j, 16);
      const uint4* p = (const uint4*)(X + (size_t)c * 128 + li * 8);
      uint4 v = *p;
      float s = (j < lim) ? 1.f : 0.f;
      a0 = fmaf(s, __uint_as_float(v.x << 16), a0);
      a1 = fmaf(s, __uint_as_float(v.x & 0xffff0000u), a1);
      a2 = fmaf(s, __uint_as_float(v.y << 16), a2);
      a3 = fmaf(s, __uint_as_float(v.y & 0xffff0000u), a3);
      a4 = fmaf(s, __uint_as_float(v.z << 16), a4);
      a5 = fmaf(s, __uint_as_float(v.z & 0xffff0000u), a5);
      a6 = fmaf(s, __uint_as_float(v.w << 16), a6);
      a7 = fmaf(s, __uint_as_float(v.w & 0xffff0000u), a7);
    }
  }

  float inv = (cnt > 0) ? 1.0f / (float)cnt : 0.f;
  uint4 o;
  o.x = ((unsigned int)f2bf(a1 * inv) << 16) | f2bf(a0 * inv);
  o.y = ((unsigned int)f2bf(a3 * inv) << 16) | f2bf(a2 * inv);
  o.z = ((unsigned int)f2bf(a5 * inv) << 16) | f2bf(a4 * inv);
  o.w = ((unsigned int)f2bf(a7 * inv) << 16) | f2bf(a6 * inv);
  *(uint4*)(out + (size_t)node * 128 + li * 8) = o;
}

// ---------------- layer-2 fused aggregate+add+ELU over P (64-dim, 128B rows) ----------
// mean commutes with W2l: out = elu(mean_j(P_j) + Q), P = h@W2l (bf16), Q = h@W2r+b2
// (f32). Rows are 128B -> 8 lanes x uint4; wave = 8 nodes; chunk of 8 edges.

__global__ void aggregate_add(const unsigned short* __restrict__ P,
                              const int* __restrict__ off, const int* __restrict__ offend,
                              const int* __restrict__ col,
                              const float* __restrict__ Q, float* __restrict__ out, int n) {
  int wv = (blockIdx.x * TPB + threadIdx.x) >> 6;
  int lane = threadIdx.x & 63;
  int li = lane & 7;
  int node = wv * 8 + (lane >> 3);
  bool alive = node < n;
  int s0 = 0, s1 = 0;
  if (alive) { s0 = off[node]; s1 = offend[node]; }
  int cnt = s1 - s0;

  float a0 = 0.f, a1 = 0.f, a2 = 0.f, a3 = 0.f,
        a4 = 0.f, a5 = 0.f, a6 = 0.f, a7 = 0.f;

  for (int base = 0; base < cnt; base += 8) {
    int ci = col[max(0, min(s0 + base + li, s1 - 1))];
    int lim = cnt - base;
#pragma unroll
    for (int j = 0; j < 8; ++j) {
      int c = __shfl(ci, j, 8);
      uint4 v = *(const uint4*)(P + (size_t)c * 64 + li * 8);
      float s = (j < lim) ? 1.f : 0.f;
      a0 = fmaf(s, __uint_as_float(v.x << 16), a0);
      a1 = fmaf(s, __uint_as_float(v.x & 0xffff0000u), a1);
      a2 = fmaf(s, __uint_as_float(v.y << 16), a2);
      a3 = fmaf(s, __uint_as_float(v.y & 0xffff0000u), a3);
      a4 = fmaf(s, __uint_as_float(v.z << 16), a4);
      a5 = fmaf(s, __uint_as_float(v.z & 0xffff0000u), a5);
      a6 = fmaf(s, __uint_as_float(v.w << 16), a6);
      a7 = fmaf(s, __uint_as_float(v.w & 0xffff0000u), a7);
    }
  }

  if (alive) {
    float inv = (cnt > 0) ? 1.0f / (float)cnt : 0.f;
    const float4* qp = (const float4*)(Q + (size_t)node * 64 + li * 8);
    float4 q0 = qp[0], q1 = qp[1];
    float4 o0, o1;
    o0.x = a0 * inv + q0.x; o0.y = a1 * inv + q0.y;
    o0.z = a2 * inv + q0.z; o0.w = a3 * inv + q0.w;
    o1.x = a4 * inv + q1.x; o1.y = a5 * inv + q1.y;
    o1.z = a6 * inv + q1.z; o1.w = a7 * inv + q1.w;
    o0.x = (o0.x > 0.f) ? o0.x : elu_neg(o0.x);
    o0.y = (o0.y > 0.f) ? o0.y : elu_neg(o0.y);
    o0.z = (o0.z > 0.f) ? o0.z : elu_neg(o0.z);
    o0.w = (o0.w > 0.f) ? o0.w : elu_neg(o0.w);
    o1.x = (o1.x > 0.f) ? o1.x : elu_neg(o1.x);
    o1.y = (o1.y > 0.f) ? o1.y : elu_neg(o1.y);
    o1.z = (o1.z > 0.f) ? o1.z : elu_neg(o1.z);
    o1.w = (o1.w > 0.f) ? o1.w : elu_neg(o1.w);
    float4* op = (float4*)(out + (size_t)node * 64 + li * 8);
    op[0] = o0; op[1] = o1;
  }
}

// ---------------- MFMA GEMM: 64x64 blocks, counted-vmcnt double-buffer ----------------
// TLP is the proven lever (R2->R3 grid 782->1564: 73->66; R7 grid 782: 76;
// all pipes <25% busy = latency-bound). 64x64 tile: grid ~3136 (12.2/CU
// offered), LDS 32KB -> 5 resident/CU (20 waves/CU), epilogue 16 vals/thread.
// XCD pair co-location kept (p = row-block shared by col-slabs y=0/1;
// g = (p>>3)*16 + y*8 + (p&7) puts both = p (mod 8) -> same XCD; R8: FETCH
// 45.7->31.8MB). NCH = K/64 chunks. MODE 0: ELU+dropout -> bf16[row][128].
// MODE 1: gcol<64 -> P bf16[row][64], gcol>=64 -> Q=v+bias f32[row][64].
// Pipeline: issue c0,c1; per chunk waitvm(4), barrier, compute (8 MFMA),
// lgkmcnt(0)+barrier, issue c+2 into freed buffer.

template <int NCH, int MODE>
__global__ __launch_bounds__(256) void gemm_mfma(
    const unsigned short* __restrict__ A1, const unsigned short* __restrict__ A2,
    const unsigned short* __restrict__ Wt, const float* __restrict__ bias,
    const unsigned char* __restrict__ dmask, unsigned short* __restrict__ outb,
    float* __restrict__ outf, int n) {
  constexpr int IPC = 4;      // DMA issues per thread per chunk: 2 A + 2 B
  constexpr int KTOT = NCH * 64;
  __shared__ __align__(16) unsigned short sA[2][64 * 64];
  __shared__ __align__(16) unsigned short sB[2][64 * 64];

  // XCD pair co-location decode: g = (p>>3)*16 + y*8 + (p&7)
  int g = blockIdx.x;
  int p = (g >> 4) * 8 + (g & 7);
  int yy = (g >> 3) & 1;
  int nrb = (n + 63) >> 6;
  if (p >= nrb) return;  // uniform for whole block; no barrier executed yet

  int tid = threadIdx.x;
  int row0 = p * 64;
  int ncol0 = yy * 64;
  int lane = tid & 63;
  int wid = tid >> 6;
  int wm = wid >> 1, wn = wid & 1;
  int lq = lane & 15, q = lane >> 4;

  int sr = tid >> 3, sc8 = tid & 7;          // staging slot: row sr (+t*32), chunk sc8
  int cg = sc8 ^ (sr & 7);                   // global chunk this lane fetches (XOR swizzle)

  // clamped A rows for the 2 staging sub-tiles (chunk-invariant)
  int arow[2];
#pragma unroll
  for (int t = 0; t < 2; ++t) arow[t] = min(row0 + sr + t * 32, n - 1);

  f32x4 acc[2][2];
#pragma unroll
  for (int i = 0; i < 2; ++i)
#pragma unroll
    for (int j = 0; j < 2; ++j) acc[i][j] = (f32x4)(0.f);

  // issue all DMA for chunk c into buffer b (IPC insts per thread)
  auto issue = [&](int c, int b) {
    const unsigned short* Asrc = (MODE == 0 && c >= NCH / 2) ? A2 : A1;
    int koff = (MODE == 0 ? (c & (NCH / 2 - 1)) : c) * 64;
#pragma unroll
    for (int t = 0; t < 2; ++t) {
      gload16(Asrc + (size_t)arow[t] * 128 + koff + cg * 8,
              (char*)sA[b] + t * 4096 + wid * 1024);
    }
#pragma unroll
    for (int t = 0; t < 2; ++t) {
      gload16(Wt + (size_t)(ncol0 + sr + t * 32) * KTOT + c * 64 + cg * 8,
              (char*)sB[b] + t * 4096 + wid * 1024);
    }
  };

  issue(0, 0);
  issue(1, 1);

#pragma unroll
  for (int c = 0; c < NCH; ++c) {
    // wait: current chunk's IPC loads landed; next chunk's may stay in flight
    if (c < NCH - 1) waitvm<IPC>(); else waitvm<0>();
    __builtin_amdgcn_s_barrier();
    __builtin_amdgcn_sched_barrier(0);

    const int buf = c & 1;
#pragma unroll
    for (int ks = 0; ks < 2; ++ks) {
      bf16x8 a[2], b[2];
#pragma unroll
      for (int i = 0; i < 2; ++i) {
        int rr = wm * 32 + i * 16 + lq;
        a[i] = *(const bf16x8*)(&sA[buf][rr * 64 + (((ks * 4 + q) ^ (rr & 7)) * 8)]);
      }
#pragma unroll
      for (int j = 0; j < 2; ++j) {
        int rb = wn * 32 + j * 16 + lq;
        b[j] = *(const bf16x8*)(&sB[buf][rb * 64 + (((ks * 4 + q) ^ (rb & 7)) * 8)]);
      }
#pragma unroll
      for (int i = 0; i < 2; ++i)
#pragma unroll
        for (int j = 0; j < 2; ++j)
          acc[i][j] = __builtin_amdgcn_mfma_f32_16x16x32_bf16(a[i], b[j], acc[i][j], 0, 0, 0);
    }

    if (c < NCH - 2) {
      // all fragment ds_reads serviced before anyone overwrites this buffer
      asm volatile("s_waitcnt lgkmcnt(0)" ::: "memory");
      __builtin_amdgcn_sched_barrier(0);
      __builtin_amdgcn_s_barrier();
      issue(c + 2, buf);
    }
  }

#pragma unroll
  for (int j = 0; j < 2; ++j) {
    int gcol = ncol0 + wn * 32 + j * 16 + lq;
    float bv;
    if (MODE == 0) bv = bias[gcol];
    else bv = (gcol >= 64) ? bias[gcol - 64] : 0.f;
#pragma unroll
    for (int i = 0; i < 2; ++i) {
      int rbase = row0 + wm * 32 + i * 16 + q * 4;
#pragma unroll
      for (int r = 0; r < 4; ++r) {
        int row = rbase + r;
        if (row >= n) continue;
        float v = acc[i][j][r] + bv;
        if (MODE == 0) {
          v = (v > 0.f) ? v : elu_neg(v);
          unsigned char k = dmask[(size_t)row * 128 + gcol];
          v = k ? v * 1.25f : 0.f;
          outb[(size_t)row * 128 + gcol] = f2bf(v);
        } else {
          if (gcol < 64) outb[(size_t)row * 64 + gcol] = f2bf(v);
          else outf[(size_t)row * 64 + (gcol - 64)] = v;
        }
      }
    }
  }
}

// ---------------- launch ----------------

extern "C" void kernel_launch(void* const* d_in, const int* in_sizes, int n_in,
                              void* d_out, int out_size, void* d_ws, size_t ws_size,
                              hipStream_t stream) {
  const float* x = (const float*)d_in[0];
  const int* ei = (const int*)d_in[1];
  const float* dropu = (const float*)d_in[2];
  const float* W1l = (const float*)d_in[3];
  const float* W1r = (const float*)d_in[4];
  const float* b1 = (const float*)d_in[5];
  const float* W2l = (const float*)d_in[6];
  const float* W2r = (const float*)d_in[7];
  const float* b2 = (const float*)d_in[8];

  int n = in_sizes[0] / 128;
  int e = in_sizes[1] / 2;
  const int* src = ei;
  const int* dst = ei + e;
  float* out = (float*)d_out;

  char* w = (char*)d_ws;
  auto alloc = [&](size_t bytes) -> char* {
    char* p = w;
    w += (bytes + 255) & ~(size_t)255;
    return p;
  };
  int nbk = (n + 127) / 128;  // buckets of 128 nodes (782)
  int* off = (int*)alloc((size_t)n * sizeof(int));
  int* offend = (int*)alloc((size_t)n * sizeof(int));
  int* col = (int*)alloc((size_t)e * sizeof(int));
  int* bcnt = (int*)alloc((size_t)(nbk + 1) * sizeof(int));  // +1: gcur cursor
  int* gcur = bcnt + nbk;
  unsigned short* xb = (unsigned short*)alloc((size_t)n * 128 * 2);
  unsigned short* hb = (unsigned short*)alloc((size_t)n * 128 * 2);
  unsigned short* aggb = (unsigned short*)alloc((size_t)n * 128 * 2);
  unsigned char* dmask = (unsigned char*)alloc((size_t)n * 128);
  unsigned short* Wt1 = (unsigned short*)alloc(128 * 256 * 2);
  unsigned short* Wt2 = (unsigned short*)alloc(128 * 128 * 2);
  // overlays (stream-ordered lifetimes):
  //   be (8.0MB)  -> aggb region: dead before agg1 writes aggb
  //   pb (12.8MB) -> xb region:   xb dead after gemm1 (A2 input)
  //   qf (25.6MB) -> aggb region: aggb dead after gemm1 (A1 input)
  unsigned int* be = (unsigned int*)aggb;
  unsigned short* pb = xb;
  float* qf = (float*)aggb;

  hipMemsetAsync(bcnt, 0, (size_t)(nbk + 1) * sizeof(int), stream);

  int gMS = (e + EPB - 1) / EPB;
  multisplit_scatter<<<gMS, TPB, 0, stream>>>(src, dst, be, bcnt, e, nbk);
  per_bucket_build<<<nbk, TPB, 0, stream>>>(be, bcnt, gcur, off, offend, col, n);

  int n4 = n * 128 / 4;
  f32_to_bf16_v4<<<(n4 + TPB - 1) / TPB, TPB, 0, stream>>>(x, xb, n4);
  make_dropmask<<<(n4 + TPB - 1) / TPB, TPB, 0, stream>>>(dropu, dmask, n4);
  build_wt<128><<<(128 * 256 + TPB - 1) / TPB, TPB, 0, stream>>>(W1l, W1r, Wt1);
  build_wt2p<<<(128 * 128 + TPB - 1) / TPB, TPB, 0, stream>>>(W2l, W2r, Wt2);

  int gAgg1 = ((n + 3) / 4 * 64 + TPB - 1) / TPB;  // 16 lanes/node, 4 nodes/wave
  int gAgg2 = (n + 31) / 32;                       // 8 lanes/node, 8 nodes/wave
  int gR = (n + 63) / 64;                          // 1563 row-blocks
  int gG = ((gR + 7) / 8) * 16;                    // XCD-paired grid (3136)

  // layer 1: agg(x) -> gemm (K=256: [agg|x]) -> elu+drop -> hb
  aggregate_bf<<<gAgg1, TPB, 0, stream>>>(xb, off, offend, col, aggb, n);
  gemm_mfma<4, 0><<<gG, TPB, 0, stream>>>(aggb, xb, Wt1, b1, dmask, hb, nullptr, n);

  // layer 2 (mean commuted with W2l): P=h@W2l (bf16), Q=h@W2r+b2 (f32),
  // out = elu(mean_j P_j + Q)
  gemm_mfma<2, 1><<<gG, TPB, 0, stream>>>(hb, nullptr, Wt2, b2, nullptr, pb, qf, n);
  aggregate_add<<<gAgg2, TPB, 0, stream>>>(pb, off, offend, col, qf, out, n);
}

// Round 10
// 380.747 us; speedup vs baseline: 1.1271x; 1.0037x over previous
//
#include <hip/hip_runtime.h>
#include <cstdint>
#include <cstddef>

#define TPB 256
#define BCAP 2560      // bucket capacity: mean 2046, sigma ~45 -> 11 sigma headroom
#define NBKMAX 800     // max buckets in LDS (n=100k -> 782)
#define EPB 8192       // edges per multisplit block

typedef short bf16x8 __attribute__((ext_vector_type(8)));
typedef float f32x4 __attribute__((ext_vector_type(4)));

__device__ __forceinline__ unsigned short f2bf(float f) {
  unsigned int u = __float_as_uint(f);
  unsigned int r = (u + 0x7fffu + ((u >> 16) & 1u)) >> 16;  // RNE
  return (unsigned short)r;
}
__device__ __forceinline__ float bf2f(unsigned short h) {
  return __uint_as_float(((unsigned int)h) << 16);
}

// fast ELU negative branch: exp(v)-1 via hardware exp; |err| ~1e-4 absolute,
// well under the bf16 rounding already applied to every intermediate.
__device__ __forceinline__ float elu_neg(float v) { return __expf(v) - 1.0f; }

// async 16B global->LDS DMA. LDS dest is wave-uniform base + lane*16.
__device__ __forceinline__ void gload16(const void* g, void* l) {
  __builtin_amdgcn_global_load_lds(
      (const __attribute__((address_space(1))) unsigned int*)g,
      (__attribute__((address_space(3))) unsigned int*)l, 16, 0, 0);
}

// counted vmcnt wait: wait until <= N vector-memory ops outstanding.
template <int N>
__device__ __forceinline__ void waitvm() {
  asm volatile("s_waitcnt vmcnt(%0)" ::"n"(N) : "memory");
}

// ---------------- bucketed CSR build (multisplit; scan-free base alloc) ----------------

__global__ __launch_bounds__(256) void multisplit_scatter(
    const int* __restrict__ src, const int* __restrict__ dst,
    unsigned int* __restrict__ be, int* __restrict__ bcnt, int e, int nbk) {
  __shared__ int hist[NBKMAX];
  __shared__ int curs[NBKMAX];
  int tx = threadIdx.x;
  int e0 = blockIdx.x * EPB;
  int e1 = min(e, e0 + EPB);

  for (int b = tx; b < nbk; b += TPB) hist[b] = 0;
  __syncthreads();
  for (int i = e0 + tx; i < e1; i += TPB) atomicAdd(&hist[dst[i] >> 7], 1);
  __syncthreads();
  int rot = (blockIdx.x * 131) % nbk;
  for (int s = tx; s < nbk; s += TPB) {
    int b = s + rot;
    if (b >= nbk) b -= nbk;
    int h = hist[b];
    curs[b] = (h > 0) ? atomicAdd(&bcnt[b], h) : 0;
  }
  __syncthreads();
  for (int i = e0 + tx; i < e1; i += TPB) {
    int d = dst[i];
    int b = d >> 7;
    int p = atomicAdd(&curs[b], 1);
    if (p < BCAP)
      be[(size_t)b * BCAP + p] = ((unsigned int)(d & 127) << 17) | (unsigned int)src[i];
  }
}

// base allocation via global cursor (gcur) -> no prefix-scan kernel, no
// cross-bucket contiguity. Per-node extent published as off[] / offend[].
__global__ __launch_bounds__(256) void per_bucket_build(
    const unsigned int* __restrict__ be, const int* __restrict__ bcnt,
    int* __restrict__ gcur, int* __restrict__ off, int* __restrict__ offend,
    int* __restrict__ col, int n) {
  int b = blockIdx.x, tx = threadIdx.x;
  int cnt = bcnt[b];
  if (cnt > BCAP) cnt = BCAP;
  int node0 = b << 7;
  __shared__ int scnt[128];
  __shared__ int sscan[128];
  __shared__ int sbase;
  if (tx < 128) scnt[tx] = 0;
  __syncthreads();
  const unsigned int* eb = be + (size_t)b * BCAP;
  for (int i = tx; i < cnt; i += 256) atomicAdd(&scnt[eb[i] >> 17], 1);
  __syncthreads();
  if (tx < 128) sscan[tx] = scnt[tx];
  __syncthreads();
  for (int d = 1; d < 128; d <<= 1) {
    int t = 0;
    if (tx < 128 && tx >= d) t = sscan[tx - d];
    __syncthreads();
    if (tx < 128) sscan[tx] += t;
    __syncthreads();
  }
  if (tx == 0) sbase = atomicAdd(gcur, cnt);
  __syncthreads();
  int base = sbase;
  if (tx < 128) {
    int excl = sscan[tx] - scnt[tx];
    if (node0 + tx < n) {
      off[node0 + tx] = base + excl;
      offend[node0 + tx] = base + sscan[tx];
    }
    scnt[tx] = excl;  // becomes fill cursor
  }
  __syncthreads();
  for (int i = tx; i < cnt; i += 256) {
    unsigned int u = eb[i];
    int p = atomicAdd(&scnt[u >> 17], 1);
    col[base + p] = (int)(u & 0x1ffff);
  }
}

// ---------------- converts ----------------

__global__ void f32_to_bf16_v4(const float* __restrict__ in, unsigned short* __restrict__ out,
                               int n4) {
  int i = blockIdx.x * TPB + threadIdx.x;
  if (i >= n4) return;
  float4 v = ((const float4*)in)[i];
  ushort4 o;
  o.x = f2bf(v.x); o.y = f2bf(v.y); o.z = f2bf(v.z); o.w = f2bf(v.w);
  ((ushort4*)out)[i] = o;
}

// layer-1 weights: Wt1[128 out][256 K] = concat(W1l;W1r) transposed
template <int NF>
__global__ void build_wt(const float* __restrict__ Wl, const float* __restrict__ Wr,
                         unsigned short* __restrict__ Wt) {
  int idx = blockIdx.x * TPB + threadIdx.x;
  if (idx >= NF * 256) return;
  int nn = idx >> 8;
  int k = idx & 255;
  float v = (k < 128) ? Wl[k * NF + nn] : Wr[(k - 128) * NF + nn];
  Wt[idx] = f2bf(v);
}

// layer-2' weights: Wt2[128 out][128 K]; rows 0-63 = W2l^T (-> P), 64-127 = W2r^T (-> Q)
__global__ void build_wt2p(const float* __restrict__ W2l, const float* __restrict__ W2r,
                           unsigned short* __restrict__ Wt) {
  int idx = blockIdx.x * TPB + threadIdx.x;
  if (idx >= 128 * 128) return;
  int nn = idx >> 7;
  int k = idx & 127;
  float v = (nn < 64) ? W2l[k * 64 + nn] : W2r[k * 64 + (nn - 64)];
  Wt[idx] = f2bf(v);
}

// ---------------- layer-1 mean aggregation: 16 lanes per node, forced 16-deep MLP -----
// R9 showed VGPR_Count=44: compiler (max-occupancy default) held only ~6-8 of
// the 16 gathers in flight. Force all 16 via explicit v[16] batch (static
// indexing) + __launch_bounds__(256,4) (4 waves/SIMD -> 128-VGPR budget,
// 16 waves/CU TLP). 32-bit byte offsets off one base -> saddr+voffset loads.
// R5 lesson bounded above (32 in flight @ 64-VGPR cap spilled); this is 16 @ 128.

__global__ __launch_bounds__(256, 4) void aggregate_bf(
    const unsigned short* __restrict__ X,
    const int* __restrict__ off, const int* __restrict__ offend,
    const int* __restrict__ col,
    unsigned short* __restrict__ out, int n) {
  int wv = (blockIdx.x * TPB + threadIdx.x) >> 6;
  int lane = threadIdx.x & 63;
  int li = lane & 15;
  int node = wv * 4 + (lane >> 4);
  if (node >= n) return;
  int s0 = off[node], s1 = offend[node];
  int cnt = s1 - s0;

  const char* Xb = (const char*)X;
  unsigned lioff = (unsigned)(li * 16);

  float a0 = 0.f, a1 = 0.f, a2 = 0.f, a3 = 0.f,
        a4 = 0.f, a5 = 0.f, a6 = 0.f, a7 = 0.f;

  for (int base = 0; base < cnt; base += 16) {
    int idx = s0 + base + li;
    int myoff = col[min(idx, s1 - 1)] << 8;  // byte offset of row (c*256)
    int lim = cnt - base;  // >0, group-uniform
    uint4 v[16];
#pragma unroll
    for (int j = 0; j < 16; ++j) {
      unsigned o = (unsigned)__shfl(myoff, j, 16) + lioff;
      v[j] = *(const uint4*)(Xb + o);
    }
#pragma unroll
    for (int j = 0; j < 16; ++j) {
      float s = (j < lim) ? 1.f : 0.f;
      a0 = fmaf(s, __uint_as_float(v[j].x << 16), a0);
      a1 = fmaf(s, __uint_as_float(v[j].x & 0xffff0000u), a1);
      a2 = fmaf(s, __uint_as_float(v[j].y << 16), a2);
      a3 = fmaf(s, __uint_as_float(v[j].y & 0xffff0000u), a3);
      a4 = fmaf(s, __uint_as_float(v[j].z << 16), a4);
      a5 = fmaf(s, __uint_as_float(v[j].z & 0xffff0000u), a5);
      a6 = fmaf(s, __uint_as_float(v[j].w << 16), a6);
      a7 = fmaf(s, __uint_as_float(v[j].w & 0xffff0000u), a7);
    }
  }

  float inv = (cnt > 0) ? 1.0f / (float)cnt : 0.f;
  uint4 o;
  o.x = ((unsigned int)f2bf(a1 * inv) << 16) | f2bf(a0 * inv);
  o.y = ((unsigned int)f2bf(a3 * inv) << 16) | f2bf(a2 * inv);
  o.z = ((unsigned int)f2bf(a5 * inv) << 16) | f2bf(a4 * inv);
  o.w = ((unsigned int)f2bf(a7 * inv) << 16) | f2bf(a6 * inv);
  *(uint4*)(out + (size_t)node * 128 + li * 8) = o;
}

// ---------------- layer-2 fused aggregate+add+ELU over P (64-dim, 128B rows) ----------
// mean commutes with W2l: out = elu(mean_j(P_j) + Q), P = h@W2l (bf16), Q = h@W2r+b2
// (f32). 8 lanes x uint4 per row; wave = 8 nodes; explicit v[8] batch as agg1.

__global__ __launch_bounds__(256, 4) void aggregate_add(
    const unsigned short* __restrict__ P,
    const int* __restrict__ off, const int* __restrict__ offend,
    const int* __restrict__ col,
    const float* __restrict__ Q, float* __restrict__ out, int n) {
  int wv = (blockIdx.x * TPB + threadIdx.x) >> 6;
  int lane = threadIdx.x & 63;
  int li = lane & 7;
  int node = wv * 8 + (lane >> 3);
  bool alive = node < n;
  int s0 = 0, s1 = 0;
  if (alive) { s0 = off[node]; s1 = offend[node]; }
  int cnt = s1 - s0;

  const char* Pb = (const char*)P;
  unsigned lioff = (unsigned)(li * 16);

  float a0 = 0.f, a1 = 0.f, a2 = 0.f, a3 = 0.f,
        a4 = 0.f, a5 = 0.f, a6 = 0.f, a7 = 0.f;

  for (int base = 0; base < cnt; base += 8) {
    int myoff = col[max(0, min(s0 + base + li, s1 - 1))] << 7;  // c*128 bytes
    int lim = cnt - base;
    uint4 v[8];
#pragma unroll
    for (int j = 0; j < 8; ++j) {
      unsigned o = (unsigned)__shfl(myoff, j, 8) + lioff;
      v[j] = *(const uint4*)(Pb + o);
    }
#pragma unroll
    for (int j = 0; j < 8; ++j) {
      float s = (j < lim) ? 1.f : 0.f;
      a0 = fmaf(s, __uint_as_float(v[j].x << 16), a0);
      a1 = fmaf(s, __uint_as_float(v[j].x & 0xffff0000u), a1);
      a2 = fmaf(s, __uint_as_float(v[j].y << 16), a2);
      a3 = fmaf(s, __uint_as_float(v[j].y & 0xffff0000u), a3);
      a4 = fmaf(s, __uint_as_float(v[j].z << 16), a4);
      a5 = fmaf(s, __uint_as_float(v[j].z & 0xffff0000u), a5);
      a6 = fmaf(s, __uint_as_float(v[j].w << 16), a6);
      a7 = fmaf(s, __uint_as_float(v[j].w & 0xffff0000u), a7);
    }
  }

  if (alive) {
    float inv = (cnt > 0) ? 1.0f / (float)cnt : 0.f;
    const float4* qp = (const float4*)(Q + (size_t)node * 64 + li * 8);
    float4 q0 = qp[0], q1 = qp[1];
    float4 o0, o1;
    o0.x = a0 * inv + q0.x; o0.y = a1 * inv + q0.y;
    o0.z = a2 * inv + q0.z; o0.w = a3 * inv + q0.w;
    o1.x = a4 * inv + q1.x; o1.y = a5 * inv + q1.y;
    o1.z = a6 * inv + q1.z; o1.w = a7 * inv + q1.w;
    o0.x = (o0.x > 0.f) ? o0.x : elu_neg(o0.x);
    o0.y = (o0.y > 0.f) ? o0.y : elu_neg(o0.y);
    o0.z = (o0.z > 0.f) ? o0.z : elu_neg(o0.z);
    o0.w = (o0.w > 0.f) ? o0.w : elu_neg(o0.w);
    o1.x = (o1.x > 0.f) ? o1.x : elu_neg(o1.x);
    o1.y = (o1.y > 0.f) ? o1.y : elu_neg(o1.y);
    o1.z = (o1.z > 0.f) ? o1.z : elu_neg(o1.z);
    o1.w = (o1.w > 0.f) ? o1.w : elu_neg(o1.w);
    float4* op = (float4*)(out + (size_t)node * 64 + li * 8);
    op[0] = o0; op[1] = o1;
  }
}

// ---------------- MFMA GEMM: 64x64 blocks, counted-vmcnt double-buffer ----------------
// TLP is the proven lever (grid ~3136, 12.2/CU offered; 32KB LDS -> 5
// resident/CU). XCD pair co-location kept. NCH = K/64 chunks.
// MODE 0: ELU + dropout read directly from dropu f32 (make_dropmask kernel
// deleted; keep = u >= 0.2f, bit-identical to reference) -> bf16[row][128].
// MODE 1: gcol<64 -> P bf16[row][64], gcol>=64 -> Q=v+bias f32[row][64].
// Pipeline: issue c0,c1; per chunk waitvm(4), barrier, compute (8 MFMA),
// lgkmcnt(0)+barrier, issue c+2 into freed buffer.

template <int NCH, int MODE>
__global__ __launch_bounds__(256) void gemm_mfma(
    const unsigned short* __restrict__ A1, const unsigned short* __restrict__ A2,
    const unsigned short* __restrict__ Wt, const float* __restrict__ bias,
    const float* __restrict__ drp, unsigned short* __restrict__ outb,
    float* __restrict__ outf, int n) {
  constexpr int IPC = 4;      // DMA issues per thread per chunk: 2 A + 2 B
  constexpr int KTOT = NCH * 64;
  __shared__ __align__(16) unsigned short sA[2][64 * 64];
  __shared__ __align__(16) unsigned short sB[2][64 * 64];

  // XCD pair co-location decode: g = (p>>3)*16 + y*8 + (p&7)
  int g = blockIdx.x;
  int p = (g >> 4) * 8 + (g & 7);
  int yy = (g >> 3) & 1;
  int nrb = (n + 63) >> 6;
  if (p >= nrb) return;  // uniform for whole block; no barrier executed yet

  int tid = threadIdx.x;
  int row0 = p * 64;
  int ncol0 = yy * 64;
  int lane = tid & 63;
  int wid = tid >> 6;
  int wm = wid >> 1, wn = wid & 1;
  int lq = lane & 15, q = lane >> 4;

  int sr = tid >> 3, sc8 = tid & 7;          // staging slot: row sr (+t*32), chunk sc8
  int cg = sc8 ^ (sr & 7);                   // global chunk this lane fetches (XOR swizzle)

  // clamped A rows for the 2 staging sub-tiles (chunk-invariant)
  int arow[2];
#pragma unroll
  for (int t = 0; t < 2; ++t) arow[t] = min(row0 + sr + t * 32, n - 1);

  f32x4 acc[2][2];
#pragma unroll
  for (int i = 0; i < 2; ++i)
#pragma unroll
    for (int j = 0; j < 2; ++j) acc[i][j] = (f32x4)(0.f);

  // issue all DMA for chunk c into buffer b (IPC insts per thread)
  auto issue = [&](int c, int b) {
    const unsigned short* Asrc = (MODE == 0 && c >= NCH / 2) ? A2 : A1;
    int koff = (MODE == 0 ? (c & (NCH / 2 - 1)) : c) * 64;
#pragma unroll
    for (int t = 0; t < 2; ++t) {
      gload16(Asrc + (size_t)arow[t] * 128 + koff + cg * 8,
              (char*)sA[b] + t * 4096 + wid * 1024);
    }
#pragma unroll
    for (int t = 0; t < 2; ++t) {
      gload16(Wt + (size_t)(ncol0 + sr + t * 32) * KTOT + c * 64 + cg * 8,
              (char*)sB[b] + t * 4096 + wid * 1024);
    }
  };

  issue(0, 0);
  issue(1, 1);

#pragma unroll
  for (int c = 0; c < NCH; ++c) {
    // wait: current chunk's IPC loads landed; next chunk's may stay in flight
    if (c < NCH - 1) waitvm<IPC>(); else waitvm<0>();
    __builtin_amdgcn_s_barrier();
    __builtin_amdgcn_sched_barrier(0);

    const int buf = c & 1;
#pragma unroll
    for (int ks = 0; ks < 2; ++ks) {
      bf16x8 a[2], b[2];
#pragma unroll
      for (int i = 0; i < 2; ++i) {
        int rr = wm * 32 + i * 16 + lq;
        a[i] = *(const bf16x8*)(&sA[buf][rr * 64 + (((ks * 4 + q) ^ (rr & 7)) * 8)]);
      }
#pragma unroll
      for (int j = 0; j < 2; ++j) {
        int rb = wn * 32 + j * 16 + lq;
        b[j] = *(const bf16x8*)(&sB[buf][rb * 64 + (((ks * 4 + q) ^ (rb & 7)) * 8)]);
      }
#pragma unroll
      for (int i = 0; i < 2; ++i)
#pragma unroll
        for (int j = 0; j < 2; ++j)
          acc[i][j] = __builtin_amdgcn_mfma_f32_16x16x32_bf16(a[i], b[j], acc[i][j], 0, 0, 0);
    }

    if (c < NCH - 2) {
      // all fragment ds_reads serviced before anyone overwrites this buffer
      asm volatile("s_waitcnt lgkmcnt(0)" ::: "memory");
      __builtin_amdgcn_sched_barrier(0);
      __builtin_amdgcn_s_barrier();
      issue(c + 2, buf);
    }
  }

#pragma unroll
  for (int j = 0; j < 2; ++j) {
    int gcol = ncol0 + wn * 32 + j * 16 + lq;
    float bv;
    if (MODE == 0) bv = bias[gcol];
    else bv = (gcol >= 64) ? bias[gcol - 64] : 0.f;
#pragma unroll
    for (int i = 0; i < 2; ++i) {
      int rbase = row0 + wm * 32 + i * 16 + q * 4;
#pragma unroll
      for (int r = 0; r < 4; ++r) {
        int row = rbase + r;
        if (row >= n) continue;
        float v = acc[i][j][r] + bv;
        if (MODE == 0) {
          v = (v > 0.f) ? v : elu_neg(v);
          float u = drp[(size_t)row * 128 + gcol];
          v = (u >= 0.2f) ? v * 1.25f : 0.f;
          outb[(size_t)row * 128 + gcol] = f2bf(v);
        } else {
          if (gcol < 64) outb[(size_t)row * 64 + gcol] = f2bf(v);
          else outf[(size_t)row * 64 + (gcol - 64)] = v;
        }
      }
    }
  }
}

// ---------------- launch ----------------

extern "C" void kernel_launch(void* const* d_in, const int* in_sizes, int n_in,
                              void* d_out, int out_size, void* d_ws, size_t ws_size,
                              hipStream_t stream) {
  const float* x = (const float*)d_in[0];
  const int* ei = (const int*)d_in[1];
  const float* dropu = (const float*)d_in[2];
  const float* W1l = (const float*)d_in[3];
  const float* W1r = (const float*)d_in[4];
  const float* b1 = (const float*)d_in[5];
  const float* W2l = (const float*)d_in[6];
  const float* W2r = (const float*)d_in[7];
  const float* b2 = (const float*)d_in[8];

  int n = in_sizes[0] / 128;
  int e = in_sizes[1] / 2;
  const int* src = ei;
  const int* dst = ei + e;
  float* out = (float*)d_out;

  char* w = (char*)d_ws;
  auto alloc = [&](size_t bytes) -> char* {
    char* p = w;
    w += (bytes + 255) & ~(size_t)255;
    return p;
  };
  int nbk = (n + 127) / 128;  // buckets of 128 nodes (782)
  int* off = (int*)alloc((size_t)n * sizeof(int));
  int* offend = (int*)alloc((size_t)n * sizeof(int));
  int* col = (int*)alloc((size_t)e * sizeof(int));
  int* bcnt = (int*)alloc((size_t)(nbk + 1) * sizeof(int));  // +1: gcur cursor
  int* gcur = bcnt + nbk;
  unsigned short* xb = (unsigned short*)alloc((size_t)n * 128 * 2);
  unsigned short* hb = (unsigned short*)alloc((size_t)n * 128 * 2);
  unsigned short* aggb = (unsigned short*)alloc((size_t)n * 128 * 2);
  unsigned short* Wt1 = (unsigned short*)alloc(128 * 256 * 2);
  unsigned short* Wt2 = (unsigned short*)alloc(128 * 128 * 2);
  // overlays (stream-ordered lifetimes):
  //   be (8.0MB)  -> aggb region: dead before agg1 writes aggb
  //   pb (12.8MB) -> xb region:   xb dead after gemm1 (A2 input)
  //   qf (25.6MB) -> aggb region: aggb dead after gemm1 (A1 input)
  unsigned int* be = (unsigned int*)aggb;
  unsigned short* pb = xb;
  float* qf = (float*)aggb;

  hipMemsetAsync(bcnt, 0, (size_t)(nbk + 1) * sizeof(int), stream);

  int gMS = (e + EPB - 1) / EPB;
  multisplit_scatter<<<gMS, TPB, 0, stream>>>(src, dst, be, bcnt, e, nbk);
  per_bucket_build<<<nbk, TPB, 0, stream>>>(be, bcnt, gcur, off, offend, col, n);

  int n4 = n * 128 / 4;
  f32_to_bf16_v4<<<(n4 + TPB - 1) / TPB, TPB, 0, stream>>>(x, xb, n4);
  build_wt<128><<<(128 * 256 + TPB - 1) / TPB, TPB, 0, stream>>>(W1l, W1r, Wt1);
  build_wt2p<<<(128 * 128 + TPB - 1) / TPB, TPB, 0, stream>>>(W2l, W2r, Wt2);

  int gAgg1 = ((n + 3) / 4 * 64 + TPB - 1) / TPB;  // 16 lanes/node, 4 nodes/wave
  int gAgg2 = (n + 31) / 32;                       // 8 lanes/node, 8 nodes/wave
  int gR = (n + 63) / 64;                          // 1563 row-blocks
  int gG = ((gR + 7) / 8) * 16;                    // XCD-paired grid (3136)

  // layer 1: agg(x) -> gemm (K=256: [agg|x]) -> elu+drop(direct dropu) -> hb
  aggregate_bf<<<gAgg1, TPB, 0, stream>>>(xb, off, offend, col, aggb, n);
  gemm_mfma<4, 0><<<gG, TPB, 0, stream>>>(aggb, xb, Wt1, b1, dropu, hb, nullptr, n);

  // layer 2 (mean commuted with W2l): P=h@W2l (bf16), Q=h@W2r+b2 (f32),
  // out = elu(mean_j P_j + Q)
  gemm_mfma<2, 1><<<gG, TPB, 0, stream>>>(hb, nullptr, Wt2, b2, nullptr, pb, qf, n);
  aggregate_add<<<gAgg2, TPB, 0, stream>>>(pb, off, offend, col, qf, out, n);
}

// Round 11
// 371.581 us; speedup vs baseline: 1.1549x; 1.0247x over previous
//
#include <hip/hip_runtime.h>
#include <cstdint>
#include <cstddef>

#define TPB 256
#define BCAP 2560      // bucket capacity: mean 2046, sigma ~45 -> 11 sigma headroom
#define NBKMAX 800     // max buckets in LDS (n=100k -> 782)
#define EPB 8192       // edges per multisplit block

typedef short bf16x8 __attribute__((ext_vector_type(8)));
typedef float f32x4 __attribute__((ext_vector_type(4)));

__device__ __forceinline__ unsigned short f2bf(float f) {
  unsigned int u = __float_as_uint(f);
  unsigned int r = (u + 0x7fffu + ((u >> 16) & 1u)) >> 16;  // RNE
  return (unsigned short)r;
}
__device__ __forceinline__ float bf2f(unsigned short h) {
  return __uint_as_float(((unsigned int)h) << 16);
}

// fast ELU negative branch: exp(v)-1 via hardware exp; |err| ~1e-4 absolute,
// well under the bf16 rounding already applied to every intermediate.
__device__ __forceinline__ float elu_neg(float v) { return __expf(v) - 1.0f; }

// async 16B global->LDS DMA. LDS dest is wave-uniform base + lane*16.
__device__ __forceinline__ void gload16(const void* g, void* l) {
  __builtin_amdgcn_global_load_lds(
      (const __attribute__((address_space(1))) unsigned int*)g,
      (__attribute__((address_space(3))) unsigned int*)l, 16, 0, 0);
}

// counted vmcnt wait: wait until <= N vector-memory ops outstanding.
template <int N>
__device__ __forceinline__ void waitvm() {
  asm volatile("s_waitcnt vmcnt(%0)" ::"n"(N) : "memory");
}

// ---------------- bucketed CSR build (multisplit; scan-free base alloc) ----------------

__global__ __launch_bounds__(256) void multisplit_scatter(
    const int* __restrict__ src, const int* __restrict__ dst,
    unsigned int* __restrict__ be, int* __restrict__ bcnt, int e, int nbk) {
  __shared__ int hist[NBKMAX];
  __shared__ int curs[NBKMAX];
  int tx = threadIdx.x;
  int e0 = blockIdx.x * EPB;
  int e1 = min(e, e0 + EPB);

  for (int b = tx; b < nbk; b += TPB) hist[b] = 0;
  __syncthreads();
  for (int i = e0 + tx; i < e1; i += TPB) atomicAdd(&hist[dst[i] >> 7], 1);
  __syncthreads();
  int rot = (blockIdx.x * 131) % nbk;
  for (int s = tx; s < nbk; s += TPB) {
    int b = s + rot;
    if (b >= nbk) b -= nbk;
    int h = hist[b];
    curs[b] = (h > 0) ? atomicAdd(&bcnt[b], h) : 0;
  }
  __syncthreads();
  for (int i = e0 + tx; i < e1; i += TPB) {
    int d = dst[i];
    int b = d >> 7;
    int p = atomicAdd(&curs[b], 1);
    if (p < BCAP)
      be[(size_t)b * BCAP + p] = ((unsigned int)(d & 127) << 17) | (unsigned int)src[i];
  }
}

// Single-pass build: stage the bucket's edges in LDS (be read ONCE, was twice),
// histogram+scan in LDS, scatter srcs to LDS by local position, then write col
// LINEARLY (coalesced) instead of 1.6M random 4B global writes.
// Base allocation via global cursor (gcur) -> no prefix-scan kernel.
__global__ __launch_bounds__(256) void per_bucket_build(
    const unsigned int* __restrict__ be, const int* __restrict__ bcnt,
    int* __restrict__ gcur, int* __restrict__ off, int* __restrict__ offend,
    int* __restrict__ col, int n) {
  int b = blockIdx.x, tx = threadIdx.x;
  int cnt = bcnt[b];
  if (cnt > BCAP) cnt = BCAP;
  int node0 = b << 7;
  __shared__ unsigned int stage[BCAP];   // packed edges (10.25 KB)
  __shared__ int ssrc[BCAP];             // srcs by local pos (10.25 KB)
  __shared__ int scnt[128];
  __shared__ int sscan[128];
  __shared__ int sbase;
  if (tx < 128) scnt[tx] = 0;
  __syncthreads();
  const unsigned int* eb = be + (size_t)b * BCAP;
  for (int i = tx; i < cnt; i += 256) stage[i] = eb[i];   // coalesced, once
  __syncthreads();
  for (int i = tx; i < cnt; i += 256) atomicAdd(&scnt[stage[i] >> 17], 1);
  __syncthreads();
  if (tx < 128) sscan[tx] = scnt[tx];
  __syncthreads();
  for (int d = 1; d < 128; d <<= 1) {
    int t = 0;
    if (tx < 128 && tx >= d) t = sscan[tx - d];
    __syncthreads();
    if (tx < 128) sscan[tx] += t;
    __syncthreads();
  }
  if (tx == 0) sbase = atomicAdd(gcur, cnt);
  __syncthreads();
  int base = sbase;
  if (tx < 128) {
    int excl = sscan[tx] - scnt[tx];
    if (node0 + tx < n) {
      off[node0 + tx] = base + excl;
      offend[node0 + tx] = base + sscan[tx];
    }
    scnt[tx] = excl;  // becomes fill cursor (local positions)
  }
  __syncthreads();
  for (int i = tx; i < cnt; i += 256) {
    unsigned int u = stage[i];
    int p = atomicAdd(&scnt[u >> 17], 1);
    ssrc[p] = (int)(u & 0x1ffff);        // LDS scatter
  }
  __syncthreads();
  for (int i = tx; i < cnt; i += 256) col[base + i] = ssrc[i];  // coalesced
}

// ---------------- fused prep: f32->bf16 convert + both weight transposes ----------

__global__ void prep_all(const float* __restrict__ x, const float* __restrict__ W1l,
                         const float* __restrict__ W1r, const float* __restrict__ W2l,
                         const float* __restrict__ W2r, unsigned short* __restrict__ xb,
                         unsigned short* __restrict__ Wt1, unsigned short* __restrict__ Wt2,
                         int n4) {
  int idx = blockIdx.x * TPB + threadIdx.x;
  if (idx < n4) {
    float4 v = ((const float4*)x)[idx];
    ushort4 o;
    o.x = f2bf(v.x); o.y = f2bf(v.y); o.z = f2bf(v.z); o.w = f2bf(v.w);
    ((ushort4*)xb)[idx] = o;
    return;
  }
  int r = idx - n4;
  if (r < 128 * 256) {  // Wt1[128 out][256 K] = concat(W1l;W1r)^T
    int nn = r >> 8;
    int k = r & 255;
    float v = (k < 128) ? W1l[k * 128 + nn] : W1r[(k - 128) * 128 + nn];
    Wt1[r] = f2bf(v);
    return;
  }
  r -= 128 * 256;
  if (r < 128 * 128) {  // Wt2[128 out][128 K]; rows 0-63 = W2l^T, 64-127 = W2r^T
    int nn = r >> 7;
    int k = r & 127;
    float v = (nn < 64) ? W2l[k * 64 + nn] : W2r[k * 64 + (nn - 64)];
    Wt2[r] = f2bf(v);
  }
}

// ---------------- layer-1 mean aggregation: 16 lanes per node (R6-form, best 66.4us) --
// One wave = 4 nodes. Per chunk of 16 edges, lane li preloads col[s0+base+li]
// (clamped), 16 unrolled j: shfl broadcast + uint4 gather + masked fma.
// Latency x MSHR bound: 410MB logical lines at ~5.9TB/s effective; 6 variants
// (scalar chain / v[16] batch / 2-node interleave / launch-bound cap) all land
// 66-70us -> structural floor. Do not touch without new counter evidence.

__global__ void aggregate_bf(const unsigned short* __restrict__ X,
                             const int* __restrict__ off, const int* __restrict__ offend,
                             const int* __restrict__ col,
                             unsigned short* __restrict__ out, int n) {
  int wv = (blockIdx.x * TPB + threadIdx.x) >> 6;
  int lane = threadIdx.x & 63;
  int li = lane & 15;
  int node = wv * 4 + (lane >> 4);
  if (node >= n) return;
  int s0 = off[node], s1 = offend[node];
  int cnt = s1 - s0;

  float a0 = 0.f, a1 = 0.f, a2 = 0.f, a3 = 0.f,
        a4 = 0.f, a5 = 0.f, a6 = 0.f, a7 = 0.f;

  for (int base = 0; base < cnt; base += 16) {
    int idx = s0 + base + li;
    int ci = col[min(idx, s1 - 1)];
    int lim = cnt - base;  // >0, group-uniform
#pragma unroll
    for (int j = 0; j < 16; ++j) {
      int c = __shfl(ci, j, 16);
      const uint4* p = (const uint4*)(X + (size_t)c * 128 + li * 8);
      uint4 v = *p;
      float s = (j < lim) ? 1.f : 0.f;
      a0 = fmaf(s, __uint_as_float(v.x << 16), a0);
      a1 = fmaf(s, __uint_as_float(v.x & 0xffff0000u), a1);
      a2 = fmaf(s, __uint_as_float(v.y << 16), a2);
      a3 = fmaf(s, __uint_as_float(v.y & 0xffff0000u), a3);
      a4 = fmaf(s, __uint_as_float(v.z << 16), a4);
      a5 = fmaf(s, __uint_as_float(v.z & 0xffff0000u), a5);
      a6 = fmaf(s, __uint_as_float(v.w << 16), a6);
      a7 = fmaf(s, __uint_as_float(v.w & 0xffff0000u), a7);
    }
  }

  float inv = (cnt > 0) ? 1.0f / (float)cnt : 0.f;
  uint4 o;
  o.x = ((unsigned int)f2bf(a1 * inv) << 16) | f2bf(a0 * inv);
  o.y = ((unsigned int)f2bf(a3 * inv) << 16) | f2bf(a2 * inv);
  o.z = ((unsigned int)f2bf(a5 * inv) << 16) | f2bf(a4 * inv);
  o.w = ((unsigned int)f2bf(a7 * inv) << 16) | f2bf(a6 * inv);
  *(uint4*)(out + (size_t)node * 128 + li * 8) = o;
}

// ---------------- layer-2 fused aggregate+add+ELU over P (64-dim, 128B rows) ----------
// mean commutes with W2l: out = elu(mean_j(P_j) + Q), P = h@W2l (bf16), Q = h@W2r+b2
// (f32). 8 lanes x uint4 per row (one cache line); wave = 8 nodes; chunk of 8 edges.

__global__ void aggregate_add(const unsigned short* __restrict__ P,
                              const int* __restrict__ off, const int* __restrict__ offend,
                              const int* __restrict__ col,
                              const float* __restrict__ Q, float* __restrict__ out, int n) {
  int wv = (blockIdx.x * TPB + threadIdx.x) >> 6;
  int lane = threadIdx.x & 63;
  int li = lane & 7;
  int node = wv * 8 + (lane >> 3);
  bool alive = node < n;
  int s0 = 0, s1 = 0;
  if (alive) { s0 = off[node]; s1 = offend[node]; }
  int cnt = s1 - s0;

  float a0 = 0.f, a1 = 0.f, a2 = 0.f, a3 = 0.f,
        a4 = 0.f, a5 = 0.f, a6 = 0.f, a7 = 0.f;

  for (int base = 0; base < cnt; base += 8) {
    int ci = col[max(0, min(s0 + base + li, s1 - 1))];
    int lim = cnt - base;
#pragma unroll
    for (int j = 0; j < 8; ++j) {
      int c = __shfl(ci, j, 8);
      uint4 v = *(const uint4*)(P + (size_t)c * 64 + li * 8);
      float s = (j < lim) ? 1.f : 0.f;
      a0 = fmaf(s, __uint_as_float(v.x << 16), a0);
      a1 = fmaf(s, __uint_as_float(v.x & 0xffff0000u), a1);
      a2 = fmaf(s, __uint_as_float(v.y << 16), a2);
      a3 = fmaf(s, __uint_as_float(v.y & 0xffff0000u), a3);
      a4 = fmaf(s, __uint_as_float(v.z << 16), a4);
      a5 = fmaf(s, __uint_as_float(v.z & 0xffff0000u), a5);
      a6 = fmaf(s, __uint_as_float(v.w << 16), a6);
      a7 = fmaf(s, __uint_as_float(v.w & 0xffff0000u), a7);
    }
  }

  if (alive) {
    float inv = (cnt > 0) ? 1.0f / (float)cnt : 0.f;
    const float4* qp = (const float4*)(Q + (size_t)node * 64 + li * 8);
    float4 q0 = qp[0], q1 = qp[1];
    float4 o0, o1;
    o0.x = a0 * inv + q0.x; o0.y = a1 * inv + q0.y;
    o0.z = a2 * inv + q0.z; o0.w = a3 * inv + q0.w;
    o1.x = a4 * inv + q1.x; o1.y = a5 * inv + q1.y;
    o1.z = a6 * inv + q1.z; o1.w = a7 * inv + q1.w;
    o0.x = (o0.x > 0.f) ? o0.x : elu_neg(o0.x);
    o0.y = (o0.y > 0.f) ? o0.y : elu_neg(o0.y);
    o0.z = (o0.z > 0.f) ? o0.z : elu_neg(o0.z);
    o0.w = (o0.w > 0.f) ? o0.w : elu_neg(o0.w);
    o1.x = (o1.x > 0.f) ? o1.x : elu_neg(o1.x);
    o1.y = (o1.y > 0.f) ? o1.y : elu_neg(o1.y);
    o1.z = (o1.z > 0.f) ? o1.z : elu_neg(o1.z);
    o1.w = (o1.w > 0.f) ? o1.w : elu_neg(o1.w);
    float4* op = (float4*)(out + (size_t)node * 64 + li * 8);
    op[0] = o0; op[1] = o1;
  }
}

// ---------------- MFMA GEMM: 64x64 blocks, counted-vmcnt double-buffer ----------------
// TLP is the proven lever (grid ~3136, 12.2/CU offered; 32KB LDS -> 5
// resident/CU). XCD pair co-location kept. NCH = K/64 chunks.
// MODE 0: ELU + dropout read directly from dropu f32 (keep = u >= 0.2f,
// bit-identical to reference) -> bf16[row][128].
// MODE 1: gcol<64 -> P bf16[row][64], gcol>=64 -> Q=v+bias f32[row][64].
// Pipeline: issue c0,c1; per chunk waitvm(4), barrier, compute (8 MFMA),
// lgkmcnt(0)+barrier, issue c+2 into freed buffer.

template <int NCH, int MODE>
__global__ __launch_bounds__(256) void gemm_mfma(
    const unsigned short* __restrict__ A1, const unsigned short* __restrict__ A2,
    const unsigned short* __restrict__ Wt, const float* __restrict__ bias,
    const float* __restrict__ drp, unsigned short* __restrict__ outb,
    float* __restrict__ outf, int n) {
  constexpr int IPC = 4;      // DMA issues per thread per chunk: 2 A + 2 B
  constexpr int KTOT = NCH * 64;
  __shared__ __align__(16) unsigned short sA[2][64 * 64];
  __shared__ __align__(16) unsigned short sB[2][64 * 64];

  // XCD pair co-location decode: g = (p>>3)*16 + y*8 + (p&7)
  int g = blockIdx.x;
  int p = (g >> 4) * 8 + (g & 7);
  int yy = (g >> 3) & 1;
  int nrb = (n + 63) >> 6;
  if (p >= nrb) return;  // uniform for whole block; no barrier executed yet

  int tid = threadIdx.x;
  int row0 = p * 64;
  int ncol0 = yy * 64;
  int lane = tid & 63;
  int wid = tid >> 6;
  int wm = wid >> 1, wn = wid & 1;
  int lq = lane & 15, q = lane >> 4;

  int sr = tid >> 3, sc8 = tid & 7;          // staging slot: row sr (+t*32), chunk sc8
  int cg = sc8 ^ (sr & 7);                   // global chunk this lane fetches (XOR swizzle)

  // clamped A rows for the 2 staging sub-tiles (chunk-invariant)
  int arow[2];
#pragma unroll
  for (int t = 0; t < 2; ++t) arow[t] = min(row0 + sr + t * 32, n - 1);

  f32x4 acc[2][2];
#pragma unroll
  for (int i = 0; i < 2; ++i)
#pragma unroll
    for (int j = 0; j < 2; ++j) acc[i][j] = (f32x4)(0.f);

  // issue all DMA for chunk c into buffer b (IPC insts per thread)
  auto issue = [&](int c, int b) {
    const unsigned short* Asrc = (MODE == 0 && c >= NCH / 2) ? A2 : A1;
    int koff = (MODE == 0 ? (c & (NCH / 2 - 1)) : c) * 64;
#pragma unroll
    for (int t = 0; t < 2; ++t) {
      gload16(Asrc + (size_t)arow[t] * 128 + koff + cg * 8,
              (char*)sA[b] + t * 4096 + wid * 1024);
    }
#pragma unroll
    for (int t = 0; t < 2; ++t) {
      gload16(Wt + (size_t)(ncol0 + sr + t * 32) * KTOT + c * 64 + cg * 8,
              (char*)sB[b] + t * 4096 + wid * 1024);
    }
  };

  issue(0, 0);
  issue(1, 1);

#pragma unroll
  for (int c = 0; c < NCH; ++c) {
    // wait: current chunk's IPC loads landed; next chunk's may stay in flight
    if (c < NCH - 1) waitvm<IPC>(); else waitvm<0>();
    __builtin_amdgcn_s_barrier();
    __builtin_amdgcn_sched_barrier(0);

    const int buf = c & 1;
#pragma unroll
    for (int ks = 0; ks < 2; ++ks) {
      bf16x8 a[2], b[2];
#pragma unroll
      for (int i = 0; i < 2; ++i) {
        int rr = wm * 32 + i * 16 + lq;
        a[i] = *(const bf16x8*)(&sA[buf][rr * 64 + (((ks * 4 + q) ^ (rr & 7)) * 8)]);
      }
#pragma unroll
      for (int j = 0; j < 2; ++j) {
        int rb = wn * 32 + j * 16 + lq;
        b[j] = *(const bf16x8*)(&sB[buf][rb * 64 + (((ks * 4 + q) ^ (rb & 7)) * 8)]);
      }
#pragma unroll
      for (int i = 0; i < 2; ++i)
#pragma unroll
        for (int j = 0; j < 2; ++j)
          acc[i][j] = __builtin_amdgcn_mfma_f32_16x16x32_bf16(a[i], b[j], acc[i][j], 0, 0, 0);
    }

    if (c < NCH - 2) {
      // all fragment ds_reads serviced before anyone overwrites this buffer
      asm volatile("s_waitcnt lgkmcnt(0)" ::: "memory");
      __builtin_amdgcn_sched_barrier(0);
      __builtin_amdgcn_s_barrier();
      issue(c + 2, buf);
    }
  }

#pragma unroll
  for (int j = 0; j < 2; ++j) {
    int gcol = ncol0 + wn * 32 + j * 16 + lq;
    float bv;
    if (MODE == 0) bv = bias[gcol];
    else bv = (gcol >= 64) ? bias[gcol - 64] : 0.f;
#pragma unroll
    for (int i = 0; i < 2; ++i) {
      int rbase = row0 + wm * 32 + i * 16 + q * 4;
#pragma unroll
      for (int r = 0; r < 4; ++r) {
        int row = rbase + r;
        if (row >= n) continue;
        float v = acc[i][j][r] + bv;
        if (MODE == 0) {
          v = (v > 0.f) ? v : elu_neg(v);
          float u = drp[(size_t)row * 128 + gcol];
          v = (u >= 0.2f) ? v * 1.25f : 0.f;
          outb[(size_t)row * 128 + gcol] = f2bf(v);
        } else {
          if (gcol < 64) outb[(size_t)row * 64 + gcol] = f2bf(v);
          else outf[(size_t)row * 64 + (gcol - 64)] = v;
        }
      }
    }
  }
}

// ---------------- launch ----------------

extern "C" void kernel_launch(void* const* d_in, const int* in_sizes, int n_in,
                              void* d_out, int out_size, void* d_ws, size_t ws_size,
                              hipStream_t stream) {
  const float* x = (const float*)d_in[0];
  const int* ei = (const int*)d_in[1];
  const float* dropu = (const float*)d_in[2];
  const float* W1l = (const float*)d_in[3];
  const float* W1r = (const float*)d_in[4];
  const float* b1 = (const float*)d_in[5];
  const float* W2l = (const float*)d_in[6];
  const float* W2r = (const float*)d_in[7];
  const float* b2 = (const float*)d_in[8];

  int n = in_sizes[0] / 128;
  int e = in_sizes[1] / 2;
  const int* src = ei;
  const int* dst = ei + e;
  float* out = (float*)d_out;

  char* w = (char*)d_ws;
  auto alloc = [&](size_t bytes) -> char* {
    char* p = w;
    w += (bytes + 255) & ~(size_t)255;
    return p;
  };
  int nbk = (n + 127) / 128;  // buckets of 128 nodes (782)
  int* off = (int*)alloc((size_t)n * sizeof(int));
  int* offend = (int*)alloc((size_t)n * sizeof(int));
  int* col = (int*)alloc((size_t)e * sizeof(int));
  int* bcnt = (int*)alloc((size_t)(nbk + 1) * sizeof(int));  // +1: gcur cursor
  int* gcur = bcnt + nbk;
  unsigned short* xb = (unsigned short*)alloc((size_t)n * 128 * 2);
  unsigned short* hb = (unsigned short*)alloc((size_t)n * 128 * 2);
  unsigned short* aggb = (unsigned short*)alloc((size_t)n * 128 * 2);
  unsigned short* Wt1 = (unsigned short*)alloc(128 * 256 * 2);
  unsigned short* Wt2 = (unsigned short*)alloc(128 * 128 * 2);
  // overlays (stream-ordered lifetimes):
  //   be (8.0MB)  -> aggb region: dead before agg1 writes aggb
  //   pb (12.8MB) -> xb region:   xb dead after gemm1 (A2 input)
  //   qf (25.6MB) -> aggb region: aggb dead after gemm1 (A1 input)
  unsigned int* be = (unsigned int*)aggb;
  unsigned short* pb = xb;
  float* qf = (float*)aggb;

  hipMemsetAsync(bcnt, 0, (size_t)(nbk + 1) * sizeof(int), stream);

  int gMS = (e + EPB - 1) / EPB;
  multisplit_scatter<<<gMS, TPB, 0, stream>>>(src, dst, be, bcnt, e, nbk);
  per_bucket_build<<<nbk, TPB, 0, stream>>>(be, bcnt, gcur, off, offend, col, n);

  int n4 = n * 128 / 4;
  int prepTot = n4 + 128 * 256 + 128 * 128;
  prep_all<<<(prepTot + TPB - 1) / TPB, TPB, 0, stream>>>(x, W1l, W1r, W2l, W2r,
                                                          xb, Wt1, Wt2, n4);

  int gAgg1 = ((n + 3) / 4 * 64 + TPB - 1) / TPB;  // 16 lanes/node, 4 nodes/wave
  int gAgg2 = (n + 31) / 32;                       // 8 lanes/node, 8 nodes/wave
  int gR = (n + 63) / 64;                          // 1563 row-blocks
  int gG = ((gR + 7) / 8) * 16;                    // XCD-paired grid (3136)

  // layer 1: agg(x) -> gemm (K=256: [agg|x]) -> elu+drop(direct dropu) -> hb
  aggregate_bf<<<gAgg1, TPB, 0, stream>>>(xb, off, offend, col, aggb, n);
  gemm_mfma<4, 0><<<gG, TPB, 0, stream>>>(aggb, xb, Wt1, b1, dropu, hb, nullptr, n);

  // layer 2 (mean commuted with W2l): P=h@W2l (bf16), Q=h@W2r+b2 (f32),
  // out = elu(mean_j P_j + Q)
  gemm_mfma<2, 1><<<gG, TPB, 0, stream>>>(hb, nullptr, Wt2, b2, nullptr, pb, qf, n);
  aggregate_add<<<gAgg2, TPB, 0, stream>>>(pb, off, offend, col, qf, out, n);
}